// Round 11
// baseline (2300.919 us; speedup 1.0000x reference)
//
#include <hip/hip_runtime.h>
#include <math.h>

typedef unsigned short ushort_t;
typedef __attribute__((ext_vector_type(8))) short short8;
typedef __attribute__((ext_vector_type(4))) float f32x4;

// ---------------- problem constants ----------------
#define Bq 2
#define Sq 1024
#define Dq 1024
#define Lq 2
#define HDq 64
#define Hq 16
#define KVq 4
#define Fq 2048
#define Eq 8
#define TOPK 2
#define Vq 32000
#define Nq (Bq*Sq)
#define EPSq 1e-5f
#define MROW (Nq*TOPK)

__device__ __forceinline__ float b2f(ushort_t u) {
  return __uint_as_float(((unsigned int)u) << 16);
}
__device__ __forceinline__ ushort_t f2b(float f) {
  unsigned int u = __float_as_uint(f);
  u += 0x7fffu + ((u >> 16) & 1u);   // RNE
  return (ushort_t)(u >> 16);
}

// ---------------- workspace layout (float offsets) ----------------
// d_out scratch (62.5 MF total; fully rewritten by final LM head):
//   attention: wQKV hi/lo [0,1.75MF) consumed pre-qk3; then
//              sc f32 [0,32MF), P hi [32MF,48MF)
//   MoE:       all-8-expert weight hi [0,8MF) + lo [8MF,16MF)
// ws O_SC region holds P lo during attention, MoE bufs during MoE, LM weight at end.
#define MF ((size_t)1024*1024)
#define O_H    ((size_t)0)
#define O_XH   (2*MF)
#define O_XL   (3*MF)
#define O_QKV  (4*MF)                 // 3 MF f32: [N][1536] q|k|v
#define O_ATH  (7*MF)
#define O_ATL  (8*MF)
#define O_QH   (9*MF)
#define O_QL   (10*MF)
#define O_KH   (11*MF)
#define O_KL   (11*MF + MF/4)
#define O_VTH  (11*MF + MF/2)
#define O_VTL  (11*MF + 3*MF/4)
#define O_COS  (12*MF)
#define O_SIN  (O_COS + 32768)
#define O_LOG  (O_SIN + 32768)
#define O_TPW  (O_LOG + 16384)
#define O_WTH  (O_COS + MF/8)         // Wo staging hi (0.5MF)
#define O_WTL  (O_WTH + MF/2)
#define O_SC   (27*MF/2)              // 13.5-29.5 : P lo (attn) / MoE h13+h3 / LM weight
// MoE overlays:
#define O_XGH  (4*MF)
#define O_XGL  (6*MF)
#define O_H13  (O_SC)
#define O_H3   (O_SC + 8*MF)
#define O_H13H (O_SC + 16*MF)
#define O_H13L (O_SC + 20*MF)
#define O_Y    (O_SC + 24*MF)
#define O_INT  (42*MF)

// ---------------- small kernels ----------------

__global__ void k_rope_table(const int* __restrict__ pos, float* __restrict__ cosT,
                             float* __restrict__ sinT) {
  int i = blockIdx.x * blockDim.x + threadIdx.x;
  if (i >= Sq * 32) return;
  int s = i >> 5, f = i & 31;
  float freq = 1.0f / powf(1.0e6f, (float)f / 32.0f);
  float ang = (float)pos[s] * freq;
  cosT[i] = cosf(ang);
  sinT[i] = sinf(ang);
}

__global__ void k_embed(const int* __restrict__ ids, const float* __restrict__ emb,
                        float* __restrict__ h) {
  int n = blockIdx.x;
  const float4* src = (const float4*)(emb + (size_t)ids[n] * Dq);
  float4* dst = (float4*)(h + (size_t)n * Dq);
  dst[threadIdx.x] = src[threadIdx.x];
}

__global__ void k_rmsnorm3(const float* __restrict__ in, const float* __restrict__ w,
                           ushort_t* __restrict__ outh, ushort_t* __restrict__ outl) {
  int n = blockIdx.x;
  int t = threadIdx.x;
  float4 v = ((const float4*)(in + (size_t)n * Dq))[t];
  float ss = v.x*v.x + v.y*v.y + v.z*v.z + v.w*v.w;
  #pragma unroll
  for (int o = 32; o > 0; o >>= 1) ss += __shfl_down(ss, o);
  __shared__ float red[4];
  if ((t & 63) == 0) red[t >> 6] = ss;
  __syncthreads();
  float tot = red[0] + red[1] + red[2] + red[3];
  float r = rsqrtf(tot / (float)Dq + EPSq);
  float4 wl = ((const float4*)w)[t];
  float o4[4];
  o4[0] = v.x * r * wl.x; o4[1] = v.y * r * wl.y;
  o4[2] = v.z * r * wl.z; o4[3] = v.w * r * wl.w;
  ushort_t* oh = outh + (size_t)n * Dq + t * 4;
  ushort_t* ol = outl + (size_t)n * Dq + t * 4;
  #pragma unroll
  for (int j = 0; j < 4; j++) {
    ushort_t hi = f2b(o4[j]);
    oh[j] = hi;
    ol[j] = f2b(o4[j] - b2f(hi));
  }
}

// fused rope + hi/lo split from combined qkv buffer (row stride 1536)
__global__ void k_rope3(const float* __restrict__ qkv, const float* __restrict__ cosT,
                        const float* __restrict__ sinT,
                        ushort_t* __restrict__ qh, ushort_t* __restrict__ ql,
                        ushort_t* __restrict__ kh, ushort_t* __restrict__ kl) {
  int i = blockIdx.x * blockDim.x + threadIdx.x;   // Nq*20*32
  int n = i / 640, r = i % 640;
  int hh = r >> 5, f = r & 31;
  int s = n & (Sq - 1);
  float c = cosT[s * 32 + f], sn = sinT[s * 32 + f];
  int srcCol = (hh < 16) ? hh * 64 + 2 * f : 1024 + (hh - 16) * 64 + 2 * f;
  const float* pp = qkv + (size_t)n * 1536 + srcCol;
  float xe = pp[0], xo = pp[1];
  float re = xe * c - xo * sn;
  float im = xe * sn + xo * c;
  ushort_t reh = f2b(re), imh = f2b(im);
  ushort_t rel = f2b(re - b2f(reh)), iml = f2b(im - b2f(imh));
  if (hh < 16) {
    size_t d = (size_t)n * 1024 + hh * 64 + 2 * f;
    qh[d] = reh; qh[d + 1] = imh;
    ql[d] = rel; ql[d + 1] = iml;
  } else {
    size_t d = (size_t)n * 256 + (hh - 16) * 64 + 2 * f;
    kh[d] = reh; kh[d + 1] = imh;
    kl[d] = rel; kl[d + 1] = iml;
  }
}

// tiled transpose + f32->bf16 hi/lo split; dl==nullptr -> hi only
__global__ void k_convT2(const float* __restrict__ src, ushort_t* __restrict__ dh,
                         ushort_t* __restrict__ dl, int srcStride, int dstStride,
                         int zdiv, long long srcZa, long long srcZb, long long dstZ) {
  __shared__ float tile[32][33];
  int z = blockIdx.z;
  const float* s = src + (long long)(z / zdiv) * srcZa + (long long)(z % zdiv) * srcZb;
  int r0 = blockIdx.y * 32, c0 = blockIdx.x * 32;
  int tc = threadIdx.x & 31, tr = threadIdx.x >> 5;
  #pragma unroll
  for (int i = 0; i < 4; ++i)
    tile[tr + i * 8][tc] = s[(long long)(r0 + tr + i * 8) * srcStride + c0 + tc];
  __syncthreads();
  #pragma unroll
  for (int i = 0; i < 4; ++i) {
    float v = tile[tc][tr + i * 8];
    ushort_t hi = f2b(v);
    long long idx = (long long)z * dstZ + (long long)(c0 + tr + i * 8) * dstStride + r0 + tc;
    dh[idx] = hi;
    if (dl) dl[idx] = f2b(v - b2f(hi));
  }
}

// ---------------- fused bf16x3 MFMA GEMM (128x128) ----------------
__global__ __launch_bounds__(256)
void k_mgemm3(const ushort_t* __restrict__ Ah, const ushort_t* __restrict__ Al,
              const ushort_t* __restrict__ Bh, const ushort_t* __restrict__ Bl,
              float* __restrict__ C,
              int N, int Kd, int lda, int ldc,
              int outmode, int mode,
              const int* __restrict__ grpBase, const int* __restrict__ grpCnt, int M) {
  __shared__ alignas(16) short Ash[128 * 64];
  __shared__ alignas(16) short Asl[128 * 64];
  __shared__ alignas(16) short Bsh[128 * 64];
  __shared__ alignas(16) short Bsl[128 * 64];
  int z = blockIdx.z;
  const ushort_t *Abh, *Abl, *Bbh, *Bbl;
  long long cOff;
  int Me = M;
  if (mode == 1) {
    int base = grpBase[z];
    Me = grpCnt[z];
    Abh = Ah + (long long)base * lda;
    Abl = Al + (long long)base * lda;
    long long bo = (long long)z * ((long long)N * Kd);
    Bbh = Bh + bo; Bbl = Bl + bo;
    cOff = (long long)base * ldc;
  } else {
    Abh = Ah; Abl = Al; Bbh = Bh; Bbl = Bl; cOff = 0;
  }
  int m0 = blockIdx.x * 128, n0 = blockIdx.y * 128;
  if (m0 >= Me) return;
  int t = threadIdx.x, w = t >> 6, lane = t & 63;
  int wm = w >> 1, wn = w & 1;
  f32x4 acc[4][4];
  #pragma unroll
  for (int i = 0; i < 4; ++i)
    #pragma unroll
    for (int j = 0; j < 4; ++j) { acc[i][j].x = 0.f; acc[i][j].y = 0.f; acc[i][j].z = 0.f; acc[i][j].w = 0.f; }
  int nkt = Kd >> 6;
  for (int kt = 0; kt < nkt; ++kt) {
    int k0 = kt << 6;
    short8 vah[4], val[4], vbh[4], vbl[4];
    #pragma unroll
    for (int p = 0; p < 4; ++p) {
      int c = t + (p << 8);
      int row = c >> 3, ch = (c & 7) << 3;
      long long ao = (long long)(m0 + row) * lda + k0 + ch;
      long long bo = (long long)(n0 + row) * Kd + k0 + ch;
      vah[p] = *(const short8*)(Abh + ao);
      val[p] = *(const short8*)(Abl + ao);
      vbh[p] = *(const short8*)(Bbh + bo);
      vbl[p] = *(const short8*)(Bbl + bo);
    }
    __syncthreads();
    #pragma unroll
    for (int p = 0; p < 4; ++p) {
      int c = t + (p << 8);
      int row = c >> 3, ch = (c & 7) << 3;
      *(short8*)&Ash[(row << 6) + ch] = vah[p];
      *(short8*)&Asl[(row << 6) + ch] = val[p];
      *(short8*)&Bsh[(row << 6) + ch] = vbh[p];
      *(short8*)&Bsl[(row << 6) + ch] = vbl[p];
    }
    __syncthreads();
    #pragma unroll
    for (int kk = 0; kk < 2; ++kk) {
      short8 afh[4], afl[4], bfh[4], bfl[4];
      int cl = (kk << 2) + (lane >> 4);
      #pragma unroll
      for (int mi = 0; mi < 4; ++mi) {
        int row = (wm << 6) + (mi << 4) + (lane & 15);
        afh[mi] = *(const short8*)&Ash[(row << 6) + (cl << 3)];
        afl[mi] = *(const short8*)&Asl[(row << 6) + (cl << 3)];
      }
      #pragma unroll
      for (int nj = 0; nj < 4; ++nj) {
        int row = (wn << 6) + (nj << 4) + (lane & 15);
        bfh[nj] = *(const short8*)&Bsh[(row << 6) + (cl << 3)];
        bfl[nj] = *(const short8*)&Bsl[(row << 6) + (cl << 3)];
      }
      #pragma unroll
      for (int mi = 0; mi < 4; ++mi)
        #pragma unroll
        for (int nj = 0; nj < 4; ++nj) {
          acc[mi][nj] = __builtin_amdgcn_mfma_f32_16x16x32_bf16(afh[mi], bfh[nj], acc[mi][nj], 0, 0, 0);
          acc[mi][nj] = __builtin_amdgcn_mfma_f32_16x16x32_bf16(afl[mi], bfh[nj], acc[mi][nj], 0, 0, 0);
          acc[mi][nj] = __builtin_amdgcn_mfma_f32_16x16x32_bf16(afh[mi], bfl[nj], acc[mi][nj], 0, 0, 0);
        }
    }
  }
  #pragma unroll
  for (int mi = 0; mi < 4; ++mi) {
    #pragma unroll
    for (int nj = 0; nj < 4; ++nj) {
      int col = n0 + (wn << 6) + (nj << 4) + (lane & 15);
      if (col >= N) continue;
      #pragma unroll
      for (int r = 0; r < 4; ++r) {
        int lr = m0 + (wm << 6) + (mi << 4) + (lane >> 4) * 4 + r;
        if (lr >= Me) continue;
        long long ci = cOff + (long long)lr * ldc + col;
        float v = ((float*)&acc[mi][nj])[r];
        if (outmode == 0) C[ci] = v;
        else C[ci] += v;
      }
    }
  }
}

// ---------------- 1-pass bf16 MFMA GEMM, 128x256 tile ----------------
__global__ __launch_bounds__(256)
void k_mgemm2(const ushort_t* __restrict__ Ah, const ushort_t* __restrict__ Bh,
              float* __restrict__ C,
              int N, int Kd, int lda, int ldc,
              int outmode, int mode,
              const int* __restrict__ grpBase, const int* __restrict__ grpCnt, int M) {
  __shared__ alignas(16) short Ash[128 * 64];
  __shared__ alignas(16) short Bsh[256 * 64];
  int z = blockIdx.z;
  const ushort_t *Abh, *Bbh;
  long long cOff;
  int Me = M;
  if (mode == 1) {
    int base = grpBase[z];
    Me = grpCnt[z];
    Abh = Ah + (long long)base * lda;
    Bbh = Bh + (long long)z * ((long long)N * Kd);
    cOff = (long long)base * ldc;
  } else {
    Abh = Ah; Bbh = Bh; cOff = 0;
  }
  int m0 = blockIdx.x * 128, n0 = blockIdx.y * 256;
  if (m0 >= Me) return;
  int t = threadIdx.x, w = t >> 6, lane = t & 63;
  int wm = w >> 1, wn = w & 1;
  f32x4 acc[4][8];
  #pragma unroll
  for (int i = 0; i < 4; ++i)
    #pragma unroll
    for (int j = 0; j < 8; ++j) { acc[i][j].x = 0.f; acc[i][j].y = 0.f; acc[i][j].z = 0.f; acc[i][j].w = 0.f; }
  int nkt = Kd >> 6;
  for (int kt = 0; kt < nkt; ++kt) {
    int k0 = kt << 6;
    short8 vah[4], vbh[8];
    #pragma unroll
    for (int p = 0; p < 4; ++p) {
      int c = t + (p << 8);
      int row = c >> 3, ch = (c & 7) << 3;
      vah[p] = *(const short8*)(Abh + (long long)(m0 + row) * lda + k0 + ch);
    }
    #pragma unroll
    for (int p = 0; p < 8; ++p) {
      int c = t + (p << 8);
      int row = c >> 3, ch = (c & 7) << 3;
      vbh[p] = *(const short8*)(Bbh + (long long)(n0 + row) * Kd + k0 + ch);
    }
    __syncthreads();
    #pragma unroll
    for (int p = 0; p < 4; ++p) {
      int c = t + (p << 8);
      int row = c >> 3, ch = (c & 7) << 3;
      *(short8*)&Ash[(row << 6) + ch] = vah[p];
    }
    #pragma unroll
    for (int p = 0; p < 8; ++p) {
      int c = t + (p << 8);
      int row = c >> 3, ch = (c & 7) << 3;
      *(short8*)&Bsh[(row << 6) + ch] = vbh[p];
    }
    __syncthreads();
    #pragma unroll
    for (int kk = 0; kk < 2; ++kk) {
      short8 afh[4], bfh[8];
      int cl = (kk << 2) + (lane >> 4);
      #pragma unroll
      for (int mi = 0; mi < 4; ++mi) {
        int row = (wm << 6) + (mi << 4) + (lane & 15);
        afh[mi] = *(const short8*)&Ash[(row << 6) + (cl << 3)];
      }
      #pragma unroll
      for (int nj = 0; nj < 8; ++nj) {
        int row = (wn << 7) + (nj << 4) + (lane & 15);
        bfh[nj] = *(const short8*)&Bsh[(row << 6) + (cl << 3)];
      }
      #pragma unroll
      for (int mi = 0; mi < 4; ++mi)
        #pragma unroll
        for (int nj = 0; nj < 8; ++nj)
          acc[mi][nj] = __builtin_amdgcn_mfma_f32_16x16x32_bf16(afh[mi], bfh[nj], acc[mi][nj], 0, 0, 0);
    }
  }
  #pragma unroll
  for (int mi = 0; mi < 4; ++mi) {
    #pragma unroll
    for (int nj = 0; nj < 8; ++nj) {
      int col = n0 + (wn << 7) + (nj << 4) + (lane & 15);
      if (col >= N) continue;
      #pragma unroll
      for (int r = 0; r < 4; ++r) {
        int lr = m0 + (wm << 6) + (mi << 4) + (lane >> 4) * 4 + r;
        if (lr >= Me) continue;
        long long ci = cOff + (long long)lr * ldc + col;
        float v = ((float*)&acc[mi][nj])[r];
        if (outmode == 0) C[ci] = v;
        else C[ci] += v;
      }
    }
  }
}

// ---------------- attention QK^T: bf16x3 MFMA, causal tile skip ---------------
__global__ __launch_bounds__(256)
void k_qk3(const ushort_t* __restrict__ qh, const ushort_t* __restrict__ ql,
           const ushort_t* __restrict__ kh, const ushort_t* __restrict__ kl,
           float* __restrict__ sc) {
  __shared__ alignas(16) short Ash[128 * 64];
  __shared__ alignas(16) short Asl[128 * 64];
  __shared__ alignas(16) short Bsh[128 * 64];
  __shared__ alignas(16) short Bsl[128 * 64];
  int zl = blockIdx.z;
  int b = zl >> 4, hh = zl & 15, kv = hh >> 2;
  int m0 = blockIdx.x * 128, n0 = blockIdx.y * 128;
  if (n0 > m0 + 127) return;
  long long aBase = ((long long)(b * Sq) * Hq + hh) * HDq;
  long long bBase = ((long long)(b * Sq) * KVq + kv) * HDq;
  int t = threadIdx.x, w = t >> 6, lane = t & 63;
  int wm = w >> 1, wn = w & 1;
  f32x4 acc[4][4];
  #pragma unroll
  for (int i = 0; i < 4; ++i)
    #pragma unroll
    for (int j = 0; j < 4; ++j) { acc[i][j].x = 0.f; acc[i][j].y = 0.f; acc[i][j].z = 0.f; acc[i][j].w = 0.f; }
  {
    short8 vah[4], val[4], vbh[4], vbl[4];
    #pragma unroll
    for (int p = 0; p < 4; ++p) {
      int c = t + (p << 8);
      int row = c >> 3, ch = (c & 7) << 3;
      long long ao = aBase + (long long)(m0 + row) * (Hq * HDq) + ch;
      long long bo = bBase + (long long)(n0 + row) * (KVq * HDq) + ch;
      vah[p] = *(const short8*)(qh + ao);
      val[p] = *(const short8*)(ql + ao);
      vbh[p] = *(const short8*)(kh + bo);
      vbl[p] = *(const short8*)(kl + bo);
    }
    __syncthreads();
    #pragma unroll
    for (int p = 0; p < 4; ++p) {
      int c = t + (p << 8);
      int row = c >> 3, ch = (c & 7) << 3;
      *(short8*)&Ash[(row << 6) + ch] = vah[p];
      *(short8*)&Asl[(row << 6) + ch] = val[p];
      *(short8*)&Bsh[(row << 6) + ch] = vbh[p];
      *(short8*)&Bsl[(row << 6) + ch] = vbl[p];
    }
    __syncthreads();
    #pragma unroll
    for (int kk = 0; kk < 2; ++kk) {
      short8 afh[4], afl[4], bfh[4], bfl[4];
      int cl = (kk << 2) + (lane >> 4);
      #pragma unroll
      for (int mi = 0; mi < 4; ++mi) {
        int row = (wm << 6) + (mi << 4) + (lane & 15);
        afh[mi] = *(const short8*)&Ash[(row << 6) + (cl << 3)];
        afl[mi] = *(const short8*)&Asl[(row << 6) + (cl << 3)];
      }
      #pragma unroll
      for (int nj = 0; nj < 4; ++nj) {
        int row = (wn << 6) + (nj << 4) + (lane & 15);
        bfh[nj] = *(const short8*)&Bsh[(row << 6) + (cl << 3)];
        bfl[nj] = *(const short8*)&Bsl[(row << 6) + (cl << 3)];
      }
      #pragma unroll
      for (int mi = 0; mi < 4; ++mi)
        #pragma unroll
        for (int nj = 0; nj < 4; ++nj) {
          acc[mi][nj] = __builtin_amdgcn_mfma_f32_16x16x32_bf16(afh[mi], bfh[nj], acc[mi][nj], 0, 0, 0);
          acc[mi][nj] = __builtin_amdgcn_mfma_f32_16x16x32_bf16(afl[mi], bfh[nj], acc[mi][nj], 0, 0, 0);
          acc[mi][nj] = __builtin_amdgcn_mfma_f32_16x16x32_bf16(afh[mi], bfl[nj], acc[mi][nj], 0, 0, 0);
        }
    }
  }
  float* out = sc + (long long)zl * Sq * Sq;
  #pragma unroll
  for (int mi = 0; mi < 4; ++mi) {
    #pragma unroll
    for (int nj = 0; nj < 4; ++nj) {
      int col = n0 + (wn << 6) + (nj << 4) + (lane & 15);
      #pragma unroll
      for (int r = 0; r < 4; ++r) {
        int lr = m0 + (wm << 6) + (mi << 4) + (lane >> 4) * 4 + r;
        out[(long long)lr * Sq + col] = ((float*)&acc[mi][nj])[r] * 0.125f;
      }
    }
  }
}

// causal softmax; reads f32 sc (32 heads), writes P hi/lo bf16
__global__ __launch_bounds__(256)
void k_softmax3(const float* __restrict__ sc, ushort_t* __restrict__ ph,
                ushort_t* __restrict__ pl) {
  int row = blockIdx.x * 4 + (threadIdx.x >> 6);   // 0 .. 32*Sq-1
  int lane = threadIdx.x & 63;
  int qi = row & (Sq - 1);
  const float* p = sc + (long long)row * Sq;
  float vals[16];
  float mx = -3.0e38f;
  #pragma unroll
  for (int j = 0; j < 16; j++) {
    int idx = lane + j * 64;
    float v = (idx <= qi) ? p[idx] : -3.0e38f;
    vals[j] = v;
    mx = fmaxf(mx, v);
  }
  #pragma unroll
  for (int o = 32; o > 0; o >>= 1) mx = fmaxf(mx, __shfl_xor(mx, o));
  float sum = 0.0f;
  #pragma unroll
  for (int j = 0; j < 16; j++) {
    int idx = lane + j * 64;
    float e = (idx <= qi) ? expf(vals[j] - mx) : 0.0f;
    vals[j] = e;
    sum += e;
  }
  #pragma unroll
  for (int o = 32; o > 0; o >>= 1) sum += __shfl_xor(sum, o);
  float inv = 1.0f / sum;
  long long base = (long long)row * Sq;
  #pragma unroll
  for (int j = 0; j < 16; j++) {
    int idx = lane + j * 64;
    float pr = vals[j] * inv;
    ushort_t hi = f2b(pr);
    ph[base + idx] = hi;
    pl[base + idx] = f2b(pr - b2f(hi));
  }
}

// attention PV: bf16x3 MFMA, triangular K bound. grid (8, 1, 32).
__global__ __launch_bounds__(256)
void k_pv3(const ushort_t* __restrict__ ph, const ushort_t* __restrict__ pl,
           const ushort_t* __restrict__ vth, const ushort_t* __restrict__ vtl,
           ushort_t* __restrict__ ath, ushort_t* __restrict__ atl) {
  __shared__ alignas(16) short Ash[128 * 64];
  __shared__ alignas(16) short Asl[128 * 64];
  __shared__ alignas(16) short Bsh[128 * 64];
  __shared__ alignas(16) short Bsl[128 * 64];
  int zl = blockIdx.z;
  int b = zl >> 4, hh = zl & 15, kv = hh >> 2;
  int m0 = blockIdx.x * 128;
  const ushort_t* Abh = ph + (long long)zl * Sq * Sq;
  const ushort_t* Abl = pl + (long long)zl * Sq * Sq;
  const ushort_t* Bbh = vth + (long long)((b * KVq + kv) * HDq) * Sq;
  const ushort_t* Bbl = vtl + (long long)((b * KVq + kv) * HDq) * Sq;
  int t = threadIdx.x, w = t >> 6, lane = t & 63;
  int wm = w >> 1, wn = w & 1;
  f32x4 acc[4][4];
  #pragma unroll
  for (int i = 0; i < 4; ++i)
    #pragma unroll
    for (int j = 0; j < 4; ++j) { acc[i][j].x = 0.f; acc[i][j].y = 0.f; acc[i][j].z = 0.f; acc[i][j].w = 0.f; }
  int ktmax = 2 * blockIdx.x + 2;      // causal: P[r][k]=0 for k > r
  for (int kt = 0; kt < ktmax; ++kt) {
    int k0 = kt << 6;
    short8 vah[4], val[4], vbh[4], vbl[4];
    #pragma unroll
    for (int p = 0; p < 4; ++p) {
      int c = t + (p << 8);
      int row = c >> 3, ch = (c & 7) << 3;
      long long ao = (long long)(m0 + row) * Sq + k0 + ch;
      long long bo = (long long)(row & 63) * Sq + k0 + ch;
      vah[p] = *(const short8*)(Abh + ao);
      val[p] = *(const short8*)(Abl + ao);
      vbh[p] = *(const short8*)(Bbh + bo);
      vbl[p] = *(const short8*)(Bbl + bo);
    }
    __syncthreads();
    #pragma unroll
    for (int p = 0; p < 4; ++p) {
      int c = t + (p << 8);
      int row = c >> 3, ch = (c & 7) << 3;
      *(short8*)&Ash[(row << 6) + ch] = vah[p];
      *(short8*)&Asl[(row << 6) + ch] = val[p];
      *(short8*)&Bsh[(row << 6) + ch] = vbh[p];
      *(short8*)&Bsl[(row << 6) + ch] = vbl[p];
    }
    __syncthreads();
    #pragma unroll
    for (int kk = 0; kk < 2; ++kk) {
      short8 afh[4], afl[4], bfh[4], bfl[4];
      int cl = (kk << 2) + (lane >> 4);
      #pragma unroll
      for (int mi = 0; mi < 4; ++mi) {
        int row = (wm << 6) + (mi << 4) + (lane & 15);
        afh[mi] = *(const short8*)&Ash[(row << 6) + (cl << 3)];
        afl[mi] = *(const short8*)&Asl[(row << 6) + (cl << 3)];
      }
      #pragma unroll
      for (int nj = 0; nj < 4; ++nj) {
        int row = (wn << 6) + (nj << 4) + (lane & 15);
        bfh[nj] = *(const short8*)&Bsh[(row << 6) + (cl << 3)];
        bfl[nj] = *(const short8*)&Bsl[(row << 6) + (cl << 3)];
      }
      #pragma unroll
      for (int mi = 0; mi < 4; ++mi)
        #pragma unroll
        for (int nj = 0; nj < 4; ++nj) {
          acc[mi][nj] = __builtin_amdgcn_mfma_f32_16x16x32_bf16(afh[mi], bfh[nj], acc[mi][nj], 0, 0, 0);
          acc[mi][nj] = __builtin_amdgcn_mfma_f32_16x16x32_bf16(afl[mi], bfh[nj], acc[mi][nj], 0, 0, 0);
          acc[mi][nj] = __builtin_amdgcn_mfma_f32_16x16x32_bf16(afh[mi], bfl[nj], acc[mi][nj], 0, 0, 0);
        }
    }
  }
  #pragma unroll
  for (int mi = 0; mi < 4; ++mi) {
    #pragma unroll
    for (int nj = 0; nj < 4; ++nj) {
      int col = (wn << 6) + (nj << 4) + (lane & 15);
      if (col >= HDq) continue;
      #pragma unroll
      for (int r = 0; r < 4; ++r) {
        int lr = m0 + (wm << 6) + (mi << 4) + (lane >> 4) * 4 + r;
        long long ci = ((long long)(b * Sq + lr)) * (Hq * HDq) + hh * HDq + col;
        float v = ((float*)&acc[mi][nj])[r];
        ushort_t hi = f2b(v);
        ath[ci] = hi;
        atl[ci] = f2b(v - b2f(hi));
      }
    }
  }
}

// ---------------- MoE routing ----------------
__global__ void k_gate(const ushort_t* __restrict__ xh, const ushort_t* __restrict__ xl,
                       const float* __restrict__ gw, float* __restrict__ logits) {
  int n = blockIdx.x * 4 + (threadIdx.x >> 6);
  int lane = threadIdx.x & 63;
  float acc[Eq];
  #pragma unroll
  for (int e = 0; e < Eq; e++) acc[e] = 0.0f;
  for (int d = lane; d < Dq; d += 64) {
    size_t idx = (size_t)n * Dq + d;
    float xv = b2f(xh[idx]) + b2f(xl[idx]);
    const float* g = gw + (size_t)d * Eq;
    #pragma unroll
    for (int e = 0; e < Eq; e++) acc[e] += xv * g[e];
  }
  #pragma unroll
  for (int o = 32; o > 0; o >>= 1)
    #pragma unroll
    for (int e = 0; e < Eq; e++) acc[e] += __shfl_xor(acc[e], o);
  if (lane == 0) {
    #pragma unroll
    for (int e = 0; e < Eq; e++) logits[(size_t)n * Eq + e] = acc[e];
  }
}

__global__ void k_zero_counts(int* c) { if (threadIdx.x < 16) c[threadIdx.x] = 0; }

__global__ void k_route_count(const float* __restrict__ logits, float* __restrict__ topw,
                              int* __restrict__ sel, int* __restrict__ counts) {
  int n = blockIdx.x * blockDim.x + threadIdx.x;
  if (n >= Nq) return;
  const float* lg = logits + (size_t)n * Eq;
  int i1 = 0; float v1 = lg[0];
  #pragma unroll
  for (int e = 1; e < Eq; e++) if (lg[e] > v1) { v1 = lg[e]; i1 = e; }
  int i2 = -1; float v2 = -3.0e38f;
  #pragma unroll
  for (int e = 0; e < Eq; e++) if (e != i1 && lg[e] > v2) { v2 = lg[e]; i2 = e; }
  float e2 = expf(v2 - v1);
  float s = 1.0f + e2;
  topw[n * 2 + 0] = 1.0f / s;
  topw[n * 2 + 1] = e2 / s;
  sel[n * 2 + 0] = i1;
  sel[n * 2 + 1] = i2;
  atomicAdd(&counts[i1], 1);
  atomicAdd(&counts[i2], 1);
}

__global__ void k_scan(const int* __restrict__ counts, int* __restrict__ bases,
                       int* __restrict__ counts2) {
  if (threadIdx.x == 0) {
    int s = 0;
    for (int e = 0; e < Eq; e++) { bases[e] = s; s += counts[e]; counts2[e] = 0; }
  }
}

__global__ void k_route_assign(const int* __restrict__ sel, int* __restrict__ counts2,
                               const int* __restrict__ bases, int* __restrict__ row2tok,
                               int* __restrict__ posof) {
  int n = blockIdx.x * blockDim.x + threadIdx.x;
  if (n >= Nq) return;
  #pragma unroll
  for (int slot = 0; slot < TOPK; slot++) {
    int e = sel[n * 2 + slot];
    int pos = atomicAdd(&counts2[e], 1);
    int row = bases[e] + pos;
    row2tok[row] = n;
    posof[n * 2 + slot] = row;
  }
}

__global__ void k_gather_us(const ushort_t* __restrict__ xh, const ushort_t* __restrict__ xl,
                            const int* __restrict__ row2tok,
                            ushort_t* __restrict__ xgh, ushort_t* __restrict__ xgl) {
  int row = blockIdx.x;
  int tok = row2tok[row];
  int t = threadIdx.x;
  const uint2* sh = (const uint2*)(xh + (size_t)tok * Dq);
  const uint2* sl = (const uint2*)(xl + (size_t)tok * Dq);
  ((uint2*)(xgh + (size_t)row * Dq))[t] = sh[t];
  ((uint2*)(xgl + (size_t)row * Dq))[t] = sl[t];
}

__global__ void k_silumul3(const float* __restrict__ h13, const float* __restrict__ h3,
                           ushort_t* __restrict__ oh, ushort_t* __restrict__ ol) {
  long total = (long)MROW * Fq;
  long i = (long)blockIdx.x * blockDim.x + threadIdx.x;
  long st = (long)gridDim.x * blockDim.x;
  for (; i < total; i += st) {
    float a = h13[i];
    float s = (a / (1.0f + expf(-a))) * h3[i];
    ushort_t hi = f2b(s);
    oh[i] = hi;
    ol[i] = f2b(s - b2f(hi));
  }
}

__global__ void k_moe_combine(float* __restrict__ h, const float* __restrict__ y,
                              const float* __restrict__ topw, const int* __restrict__ posof) {
  int n = blockIdx.x;
  int t = threadIdx.x;
  float w0 = topw[n * 2 + 0], w1 = topw[n * 2 + 1];
  int r0 = posof[n * 2 + 0], r1 = posof[n * 2 + 1];
  float4 a = ((const float4*)(y + (size_t)r0 * Dq))[t];
  float4 b = ((const float4*)(y + (size_t)r1 * Dq))[t];
  float4 hv = ((float4*)(h + (size_t)n * Dq))[t];
  hv.x += w0 * a.x + w1 * b.x;
  hv.y += w0 * a.y + w1 * b.y;
  hv.z += w0 * a.z + w1 * b.z;
  hv.w += w0 * a.w + w1 * b.w;
  ((float4*)(h + (size_t)n * Dq))[t] = hv;
}

// ---------------- launch ----------------
extern "C" void kernel_launch(void* const* d_in, const int* in_sizes, int n_in,
                              void* d_out, int out_size, void* d_ws, size_t ws_size,
                              hipStream_t stream) {
  const int* ids       = (const int*)d_in[0];
  const int* pos       = (const int*)d_in[1];
  const float* tok_emb = (const float*)d_in[2];
  const float* attn_nw = (const float*)d_in[3];
  const float* ffn_nw  = (const float*)d_in[4];
  const float* wq      = (const float*)d_in[5];
  const float* wk      = (const float*)d_in[6];
  const float* wv      = (const float*)d_in[7];
  const float* wo      = (const float*)d_in[8];
  const float* gate    = (const float*)d_in[9];
  const float* w1      = (const float*)d_in[10];
  const float* w2      = (const float*)d_in[11];
  const float* w3      = (const float*)d_in[12];
  const float* fnw     = (const float*)d_in[13];
  const float* outw    = (const float*)d_in[14];
  float* out = (float*)d_out;
  float* ws = (float*)d_ws;
  float* dws = out;   // phase scratch inside d_out (62.5 MF; fully rewritten by LM head)

  float* h      = ws + O_H;
  ushort_t* xh  = (ushort_t*)(ws + O_XH);
  ushort_t* xl  = (ushort_t*)(ws + O_XL);
  float* qkv    = ws + O_QKV;
  ushort_t* ath = (ushort_t*)(ws + O_ATH);
  ushort_t* atl = (ushort_t*)(ws + O_ATL);
  ushort_t* qhB = (ushort_t*)(ws + O_QH);
  ushort_t* qlB = (ushort_t*)(ws + O_QL);
  ushort_t* khB = (ushort_t*)(ws + O_KH);
  ushort_t* klB = (ushort_t*)(ws + O_KL);
  ushort_t* vth = (ushort_t*)(ws + O_VTH);
  ushort_t* vtl = (ushort_t*)(ws + O_VTL);
  float* cosT   = ws + O_COS;
  float* sinT   = ws + O_SIN;
  float* logits = ws + O_LOG;
  float* topw   = ws + O_TPW;
  ushort_t* wTh = (ushort_t*)(ws + O_WTH);
  ushort_t* wTl = (ushort_t*)(ws + O_WTL);
  float* sc     = dws;                          // 32 heads f32 scores (32MF)
  ushort_t* ph  = (ushort_t*)(dws + 32*MF);     // P hi (16MF)
  ushort_t* pl  = (ushort_t*)(ws + O_SC);       // P lo (16MF, ws dead region)
  ushort_t* wQh = (ushort_t*)dws;               // QKV weight hi (consumed pre-qk3)
  ushort_t* wQl = (ushort_t*)(dws + MF);
  ushort_t* xgh = (ushort_t*)(ws + O_XGH);
  ushort_t* xgl = (ushort_t*)(ws + O_XGL);
  ushort_t* wAh = (ushort_t*)dws;               // expert weight hi (8MF)
  ushort_t* wAl = (ushort_t*)(dws + 8*MF);      // expert weight lo
  float* h13    = ws + O_H13;
  float* h3     = ws + O_H3;
  ushort_t* h13h= (ushort_t*)(ws + O_H13H);
  ushort_t* h13l= (ushort_t*)(ws + O_H13L);
  float* y      = ws + O_Y;
  ushort_t* owTh= (ushort_t*)(ws + O_SC);       // LM weight hi (15.7MF of 16MF region)
  int* ip = (int*)(ws + O_INT);
  int* counts  = ip;
  int* counts2 = ip + 8;
  int* bases   = ip + 16;
  int* sel     = ip + 32;
  int* row2tok = ip + 32 + 4096;
  int* posof   = ip + 32 + 8192;

  k_rope_table<<<128, 256, 0, stream>>>(pos, cosT, sinT);
  k_embed<<<Nq, 256, 0, stream>>>(ids, tok_emb, h);

  for (int l = 0; l < Lq; l++) {
    // ---- attention ----
    k_rmsnorm3<<<Nq, 256, 0, stream>>>(h, attn_nw + (size_t)l * Dq, xh, xl);
    // stage combined [wq|wk|wv]^T into d_out scratch
    k_convT2<<<dim3(32, 32, 1), 256, 0, stream>>>(wq + (long long)l*Dq*Hq*HDq, wQh, wQl, Hq*HDq, Dq, 1, 0, 0, 0);
    k_convT2<<<dim3(8, 32, 1), 256, 0, stream>>>(wk + (long long)l*Dq*KVq*HDq, wQh + (size_t)1024*1024, wQl + (size_t)1024*1024, KVq*HDq, Dq, 1, 0, 0, 0);
    k_convT2<<<dim3(8, 32, 1), 256, 0, stream>>>(wv + (long long)l*Dq*KVq*HDq, wQh + (size_t)1280*1024, wQl + (size_t)1280*1024, KVq*HDq, Dq, 1, 0, 0, 0);
    // fused QKV projection -> qkv [N][1536]
    k_mgemm3<<<dim3(16, 12, 1), 256, 0, stream>>>(xh, xl, wQh, wQl, qkv, 1536, Dq, Dq, 1536, 0, 0, nullptr, nullptr, Nq);
    // rope + hi/lo split for q,k
    k_rope3<<<(Nq * 20 * 32) / 256, 256, 0, stream>>>(qkv, cosT, sinT, qhB, qlB, khB, klB);
    // vT hi/lo from qkv (v at col 1280, row stride 1536)
    k_convT2<<<dim3(2, 32, Bq*KVq), 256, 0, stream>>>(qkv + 1280, vth, vtl, 1536, Sq,
           KVq, (long long)Sq*1536, HDq, (long long)HDq*Sq);
    // all 32 heads in one pass (sc + P hi in d_out, P lo in ws)
    k_qk3<<<dim3(8, 8, 32), 256, 0, stream>>>(qhB, qlB, khB, klB, sc);
    k_softmax3<<<(32 * Sq) / 4, 256, 0, stream>>>(sc, ph, pl);
    k_pv3<<<dim3(8, 1, 32), 256, 0, stream>>>(ph, pl, vth, vtl, ath, atl);
    k_convT2<<<dim3(32, 32, 1), 256, 0, stream>>>(wo + (long long)l*Hq*HDq*Dq, wTh, wTl, Dq, Hq*HDq, 1, 0, 0, 0);
    k_mgemm3<<<dim3(16, 8, 1), 256, 0, stream>>>(ath, atl, wTh, wTl, h, Dq, Hq*HDq, Hq*HDq, Dq, 1, 0, nullptr, nullptr, Nq);

    // ---- MoE ----
    k_rmsnorm3<<<Nq, 256, 0, stream>>>(h, ffn_nw + (size_t)l * Dq, xh, xl);
    k_gate<<<Nq / 4, 256, 0, stream>>>(xh, xl, gate + (size_t)l * Dq * Eq, logits);
    k_zero_counts<<<1, 32, 0, stream>>>(counts);
    k_route_count<<<Nq / 256, 256, 0, stream>>>(logits, topw, sel, counts);
    k_scan<<<1, 1, 0, stream>>>(counts, bases, counts2);
    k_route_assign<<<Nq / 256, 256, 0, stream>>>(sel, counts2, bases, row2tok, posof);
    k_gather_us<<<MROW, 256, 0, stream>>>(xh, xl, row2tok, xgh, xgl);
    int last = (l == Lq - 1);   // no routing downstream of last MoE -> 1-pass bf16
    // w1
    k_convT2<<<dim3(64, 32, 8), 256, 0, stream>>>(w1 + (long long)l*Eq*Dq*Fq, wAh, last ? nullptr : wAl, Fq, Dq, 1, (long long)Dq*Fq, 0, (long long)Fq*Dq);
    if (last) k_mgemm2<<<dim3(16, 8, 8), 256, 0, stream>>>(xgh, wAh, h13, Fq, Dq, Dq, Fq, 0, 1, bases, counts, 0);
    else      k_mgemm3<<<dim3(16, 16, 8), 256, 0, stream>>>(xgh, xgl, wAh, wAl, h13, Fq, Dq, Dq, Fq, 0, 1, bases, counts, 0);
    // w3
    k_convT2<<<dim3(64, 32, 8), 256, 0, stream>>>(w3 + (long long)l*Eq*Dq*Fq, wAh, last ? nullptr : wAl, Fq, Dq, 1, (long long)Dq*Fq, 0, (long long)Fq*Dq);
    if (last) k_mgemm2<<<dim3(16, 8, 8), 256, 0, stream>>>(xgh, wAh, h3, Fq, Dq, Dq, Fq, 0, 1, bases, counts, 0);
    else      k_mgemm3<<<dim3(16, 16, 8), 256, 0, stream>>>(xgh, xgl, wAh, wAl, h3, Fq, Dq, Dq, Fq, 0, 1, bases, counts, 0);
    k_silumul3<<<4096, 256, 0, stream>>>(h13, h3, h13h, h13l);
    // w2
    k_convT2<<<dim3(32, 64, 8), 256, 0, stream>>>(w2 + (long long)l*Eq*Fq*Dq, wAh, last ? nullptr : wAl, Dq, Fq, 1, (long long)Fq*Dq, 0, (long long)Dq*Fq);
    if (last) k_mgemm2<<<dim3(16, 4, 8), 256, 0, stream>>>(h13h, wAh, y, Dq, Fq, Fq, Dq, 0, 1, bases, counts, 0);
    else      k_mgemm3<<<dim3(16, 8, 8), 256, 0, stream>>>(h13h, h13l, wAh, wAl, y, Dq, Fq, Fq, Dq, 0, 1, bases, counts, 0);
    k_moe_combine<<<Nq, 256, 0, stream>>>(h, y, topw, posof);
  }

  // ---- final norm + LM head (1-pass bf16, 128x256 tile) ----
  k_rmsnorm3<<<Nq, 256, 0, stream>>>(h, fnw, xh, xl);
  k_convT2<<<dim3(1000, 32, 1), 256, 0, stream>>>(outw, owTh, nullptr, Vq, Dq, 1, 0, 0, 0);
  k_mgemm2<<<dim3(16, 125, 1), 256, 0, stream>>>(xh, owTh, out, Vq, Dq, Dq, Vq, 0, 0, nullptr, nullptr, Nq);
}

// Round 12
// 1829.451 us; speedup vs baseline: 1.2577x; 1.2577x over previous
//
#include <hip/hip_runtime.h>
#include <math.h>

typedef unsigned short ushort_t;
typedef __attribute__((ext_vector_type(8))) short short8;
typedef __attribute__((ext_vector_type(4))) float f32x4;

// ---------------- problem constants ----------------
#define Bq 2
#define Sq 1024
#define Dq 1024
#define Lq 2
#define HDq 64
#define Hq 16
#define KVq 4
#define Fq 2048
#define Eq 8
#define TOPK 2
#define Vq 32000
#define Nq (Bq*Sq)
#define EPSq 1e-5f
#define MROW (Nq*TOPK)

__device__ __forceinline__ float b2f(ushort_t u) {
  return __uint_as_float(((unsigned int)u) << 16);
}
__device__ __forceinline__ ushort_t f2b(float f) {
  unsigned int u = __float_as_uint(f);
  u += 0x7fffu + ((u >> 16) & 1u);   // RNE
  return (ushort_t)(u >> 16);
}

// async global->LDS (16B per lane; LDS dest = wave-uniform base + lane*16)
typedef const void __attribute__((address_space(1)))* gas_cptr;
typedef void __attribute__((address_space(3)))* las_ptr;
__device__ __forceinline__ void gload16(const void* g, void* l) {
  __builtin_amdgcn_global_load_lds((gas_cptr)g, (las_ptr)l, 16, 0, 0);
}

// ---------------- workspace layout (float offsets) ----------------
#define MF ((size_t)1024*1024)
#define O_H    ((size_t)0)
#define O_XH   (2*MF)
#define O_XL   (3*MF)
#define O_QKV  (4*MF)                 // 3 MF f32: [N][1536] q|k|v
#define O_ATH  (7*MF)
#define O_ATL  (8*MF)
#define O_QH   (9*MF)
#define O_QL   (10*MF)
#define O_KH   (11*MF)
#define O_KL   (11*MF + MF/4)
#define O_VTH  (11*MF + MF/2)
#define O_VTL  (11*MF + 3*MF/4)
#define O_COS  (12*MF)
#define O_SIN  (O_COS + 32768)
#define O_LOG  (O_SIN + 32768)
#define O_TPW  (O_LOG + 16384)
#define O_WTH  (O_COS + MF/8)         // Wo staging hi (0.5MF)
#define O_WTL  (O_WTH + MF/2)
#define O_SC   (27*MF/2)              // P lo (attn) / MoE bufs / LM weight
// MoE overlays:
#define O_XGH  (4*MF)
#define O_XGL  (6*MF)
#define O_H13  (O_SC)
#define O_H3   (O_SC + 8*MF)
#define O_H13H (O_SC + 16*MF)
#define O_H13L (O_SC + 20*MF)
#define O_Y    (O_SC + 24*MF)
#define O_INT  (42*MF)

// ---------------- small kernels ----------------

__global__ void k_rope_table(const int* __restrict__ pos, float* __restrict__ cosT,
                             float* __restrict__ sinT) {
  int i = blockIdx.x * blockDim.x + threadIdx.x;
  if (i >= Sq * 32) return;
  int s = i >> 5, f = i & 31;
  float freq = 1.0f / powf(1.0e6f, (float)f / 32.0f);
  float ang = (float)pos[s] * freq;
  cosT[i] = cosf(ang);
  sinT[i] = sinf(ang);
}

__global__ void k_embed(const int* __restrict__ ids, const float* __restrict__ emb,
                        float* __restrict__ h) {
  int n = blockIdx.x;
  const float4* src = (const float4*)(emb + (size_t)ids[n] * Dq);
  float4* dst = (float4*)(h + (size_t)n * Dq);
  dst[threadIdx.x] = src[threadIdx.x];
}

__global__ void k_rmsnorm3(const float* __restrict__ in, const float* __restrict__ w,
                           ushort_t* __restrict__ outh, ushort_t* __restrict__ outl) {
  int n = blockIdx.x;
  int t = threadIdx.x;
  float4 v = ((const float4*)(in + (size_t)n * Dq))[t];
  float ss = v.x*v.x + v.y*v.y + v.z*v.z + v.w*v.w;
  #pragma unroll
  for (int o = 32; o > 0; o >>= 1) ss += __shfl_down(ss, o);
  __shared__ float red[4];
  if ((t & 63) == 0) red[t >> 6] = ss;
  __syncthreads();
  float tot = red[0] + red[1] + red[2] + red[3];
  float r = rsqrtf(tot / (float)Dq + EPSq);
  float4 wl = ((const float4*)w)[t];
  float o4[4];
  o4[0] = v.x * r * wl.x; o4[1] = v.y * r * wl.y;
  o4[2] = v.z * r * wl.z; o4[3] = v.w * r * wl.w;
  ushort_t* oh = outh + (size_t)n * Dq + t * 4;
  ushort_t* ol = outl + (size_t)n * Dq + t * 4;
  #pragma unroll
  for (int j = 0; j < 4; j++) {
    ushort_t hi = f2b(o4[j]);
    oh[j] = hi;
    ol[j] = f2b(o4[j] - b2f(hi));
  }
}

// fused rope + hi/lo split from combined qkv buffer (row stride 1536)
__global__ void k_rope3(const float* __restrict__ qkv, const float* __restrict__ cosT,
                        const float* __restrict__ sinT,
                        ushort_t* __restrict__ qh, ushort_t* __restrict__ ql,
                        ushort_t* __restrict__ kh, ushort_t* __restrict__ kl) {
  int i = blockIdx.x * blockDim.x + threadIdx.x;   // Nq*20*32
  int n = i / 640, r = i % 640;
  int hh = r >> 5, f = r & 31;
  int s = n & (Sq - 1);
  float c = cosT[s * 32 + f], sn = sinT[s * 32 + f];
  int srcCol = (hh < 16) ? hh * 64 + 2 * f : 1024 + (hh - 16) * 64 + 2 * f;
  const float* pp = qkv + (size_t)n * 1536 + srcCol;
  float xe = pp[0], xo = pp[1];
  float re = xe * c - xo * sn;
  float im = xe * sn + xo * c;
  ushort_t reh = f2b(re), imh = f2b(im);
  ushort_t rel = f2b(re - b2f(reh)), iml = f2b(im - b2f(imh));
  if (hh < 16) {
    size_t d = (size_t)n * 1024 + hh * 64 + 2 * f;
    qh[d] = reh; qh[d + 1] = imh;
    ql[d] = rel; ql[d + 1] = iml;
  } else {
    size_t d = (size_t)n * 256 + (hh - 16) * 64 + 2 * f;
    kh[d] = reh; kh[d + 1] = imh;
    kl[d] = rel; kl[d + 1] = iml;
  }
}

// tiled transpose + f32->bf16 hi/lo split; dl==nullptr -> hi only
__global__ void k_convT2(const float* __restrict__ src, ushort_t* __restrict__ dh,
                         ushort_t* __restrict__ dl, int srcStride, int dstStride,
                         int zdiv, long long srcZa, long long srcZb, long long dstZ) {
  __shared__ float tile[32][33];
  int z = blockIdx.z;
  const float* s = src + (long long)(z / zdiv) * srcZa + (long long)(z % zdiv) * srcZb;
  int r0 = blockIdx.y * 32, c0 = blockIdx.x * 32;
  int tc = threadIdx.x & 31, tr = threadIdx.x >> 5;
  #pragma unroll
  for (int i = 0; i < 4; ++i)
    tile[tr + i * 8][tc] = s[(long long)(r0 + tr + i * 8) * srcStride + c0 + tc];
  __syncthreads();
  #pragma unroll
  for (int i = 0; i < 4; ++i) {
    float v = tile[tc][tr + i * 8];
    ushort_t hi = f2b(v);
    long long idx = (long long)z * dstZ + (long long)(c0 + tr + i * 8) * dstStride + r0 + tc;
    dh[idx] = hi;
    if (dl) dl[idx] = f2b(v - b2f(hi));
  }
}

// ---------------- fused bf16x3 MFMA GEMM (gload_lds + XOR swizzle) ----------
__global__ __launch_bounds__(256)
void k_mgemm3(const ushort_t* __restrict__ Ah, const ushort_t* __restrict__ Al,
              const ushort_t* __restrict__ Bh, const ushort_t* __restrict__ Bl,
              float* __restrict__ C,
              int N, int Kd, int lda, int ldc,
              int outmode, int mode,
              const int* __restrict__ grpBase, const int* __restrict__ grpCnt, int M) {
  __shared__ alignas(16) short Ash[128 * 64];
  __shared__ alignas(16) short Asl[128 * 64];
  __shared__ alignas(16) short Bsh[128 * 64];
  __shared__ alignas(16) short Bsl[128 * 64];
  int z = blockIdx.z;
  const ushort_t *Abh, *Abl, *Bbh, *Bbl;
  long long cOff;
  int Me = M;
  if (mode == 1) {
    int base = grpBase[z];
    Me = grpCnt[z];
    Abh = Ah + (long long)base * lda;
    Abl = Al + (long long)base * lda;
    long long bo = (long long)z * ((long long)N * Kd);
    Bbh = Bh + bo; Bbl = Bl + bo;
    cOff = (long long)base * ldc;
  } else {
    Abh = Ah; Abl = Al; Bbh = Bh; Bbl = Bl; cOff = 0;
  }
  int m0 = blockIdx.x * 128, n0 = blockIdx.y * 128;
  if (m0 >= Me) return;
  int t = threadIdx.x, w = t >> 6, lane = t & 63;
  int wm = w >> 1, wn = w & 1;
  int rA = lane >> 3;
  int sOff = ((lane & 7) ^ rA) << 3;     // inverse-swizzled source chunk (elements)
  f32x4 acc[4][4];
  #pragma unroll
  for (int i = 0; i < 4; ++i)
    #pragma unroll
    for (int j = 0; j < 4; ++j) { acc[i][j].x = 0.f; acc[i][j].y = 0.f; acc[i][j].z = 0.f; acc[i][j].w = 0.f; }
  int nkt = Kd >> 6;
  for (int kt = 0; kt < nkt; ++kt) {
    int k0 = kt << 6;
    #pragma unroll
    for (int i = 0; i < 4; ++i) {
      int j = (w << 2) + i;
      int row = (j << 3) + rA;
      long long ao = (long long)(m0 + row) * lda + k0 + sOff;
      long long bo = (long long)(n0 + row) * Kd + k0 + sOff;
      gload16(Abh + ao, &Ash[j * 512]);
      gload16(Abl + ao, &Asl[j * 512]);
      gload16(Bbh + bo, &Bsh[j * 512]);
      gload16(Bbl + bo, &Bsl[j * 512]);
    }
    __syncthreads();
    #pragma unroll
    for (int kk = 0; kk < 2; ++kk) {
      short8 afh[4], afl[4], bfh[4], bfl[4];
      int cl = (kk << 2) + (lane >> 4);
      #pragma unroll
      for (int mi = 0; mi < 4; ++mi) {
        int row = (wm << 6) + (mi << 4) + (lane & 15);
        int idx = (row << 6) + ((cl ^ (row & 7)) << 3);
        afh[mi] = *(const short8*)&Ash[idx];
        afl[mi] = *(const short8*)&Asl[idx];
      }
      #pragma unroll
      for (int nj = 0; nj < 4; ++nj) {
        int row = (wn << 6) + (nj << 4) + (lane & 15);
        int idx = (row << 6) + ((cl ^ (row & 7)) << 3);
        bfh[nj] = *(const short8*)&Bsh[idx];
        bfl[nj] = *(const short8*)&Bsl[idx];
      }
      #pragma unroll
      for (int mi = 0; mi < 4; ++mi)
        #pragma unroll
        for (int nj = 0; nj < 4; ++nj) {
          acc[mi][nj] = __builtin_amdgcn_mfma_f32_16x16x32_bf16(afh[mi], bfh[nj], acc[mi][nj], 0, 0, 0);
          acc[mi][nj] = __builtin_amdgcn_mfma_f32_16x16x32_bf16(afl[mi], bfh[nj], acc[mi][nj], 0, 0, 0);
          acc[mi][nj] = __builtin_amdgcn_mfma_f32_16x16x32_bf16(afh[mi], bfl[nj], acc[mi][nj], 0, 0, 0);
        }
    }
    __syncthreads();
  }
  #pragma unroll
  for (int mi = 0; mi < 4; ++mi) {
    #pragma unroll
    for (int nj = 0; nj < 4; ++nj) {
      int col = n0 + (wn << 6) + (nj << 4) + (lane & 15);
      if (col >= N) continue;
      #pragma unroll
      for (int r = 0; r < 4; ++r) {
        int lr = m0 + (wm << 6) + (mi << 4) + (lane >> 4) * 4 + r;
        if (lr >= Me) continue;
        long long ci = cOff + (long long)lr * ldc + col;
        float v = ((float*)&acc[mi][nj])[r];
        if (outmode == 0) C[ci] = v;
        else C[ci] += v;
      }
    }
  }
}

// ---------------- 1-pass bf16 MFMA GEMM (gload_lds + XOR swizzle) ------------
__global__ __launch_bounds__(256)
void k_mgemm1(const ushort_t* __restrict__ Ah, const ushort_t* __restrict__ Bh,
              float* __restrict__ C,
              int N, int Kd, int lda, int ldc,
              int outmode, int mode,
              const int* __restrict__ grpBase, const int* __restrict__ grpCnt, int M) {
  __shared__ alignas(16) short Ash[128 * 64];
  __shared__ alignas(16) short Bsh[128 * 64];
  int z = blockIdx.z;
  const ushort_t *Abh, *Bbh;
  long long cOff;
  int Me = M;
  if (mode == 1) {
    int base = grpBase[z];
    Me = grpCnt[z];
    Abh = Ah + (long long)base * lda;
    Bbh = Bh + (long long)z * ((long long)N * Kd);
    cOff = (long long)base * ldc;
  } else {
    Abh = Ah; Bbh = Bh; cOff = 0;
  }
  int m0 = blockIdx.x * 128, n0 = blockIdx.y * 128;
  if (m0 >= Me) return;
  int t = threadIdx.x, w = t >> 6, lane = t & 63;
  int wm = w >> 1, wn = w & 1;
  int rA = lane >> 3;
  int sOff = ((lane & 7) ^ rA) << 3;
  f32x4 acc[4][4];
  #pragma unroll
  for (int i = 0; i < 4; ++i)
    #pragma unroll
    for (int j = 0; j < 4; ++j) { acc[i][j].x = 0.f; acc[i][j].y = 0.f; acc[i][j].z = 0.f; acc[i][j].w = 0.f; }
  int nkt = Kd >> 6;
  for (int kt = 0; kt < nkt; ++kt) {
    int k0 = kt << 6;
    #pragma unroll
    for (int i = 0; i < 4; ++i) {
      int j = (w << 2) + i;
      int row = (j << 3) + rA;
      gload16(Abh + (long long)(m0 + row) * lda + k0 + sOff, &Ash[j * 512]);
      gload16(Bbh + (long long)(n0 + row) * Kd + k0 + sOff, &Bsh[j * 512]);
    }
    __syncthreads();
    #pragma unroll
    for (int kk = 0; kk < 2; ++kk) {
      short8 afh[4], bfh[4];
      int cl = (kk << 2) + (lane >> 4);
      #pragma unroll
      for (int mi = 0; mi < 4; ++mi) {
        int row = (wm << 6) + (mi << 4) + (lane & 15);
        afh[mi] = *(const short8*)&Ash[(row << 6) + ((cl ^ (row & 7)) << 3)];
      }
      #pragma unroll
      for (int nj = 0; nj < 4; ++nj) {
        int row = (wn << 6) + (nj << 4) + (lane & 15);
        bfh[nj] = *(const short8*)&Bsh[(row << 6) + ((cl ^ (row & 7)) << 3)];
      }
      #pragma unroll
      for (int mi = 0; mi < 4; ++mi)
        #pragma unroll
        for (int nj = 0; nj < 4; ++nj)
          acc[mi][nj] = __builtin_amdgcn_mfma_f32_16x16x32_bf16(afh[mi], bfh[nj], acc[mi][nj], 0, 0, 0);
    }
    __syncthreads();
  }
  #pragma unroll
  for (int mi = 0; mi < 4; ++mi) {
    #pragma unroll
    for (int nj = 0; nj < 4; ++nj) {
      int col = n0 + (wn << 6) + (nj << 4) + (lane & 15);
      if (col >= N) continue;
      #pragma unroll
      for (int r = 0; r < 4; ++r) {
        int lr = m0 + (wm << 6) + (mi << 4) + (lane >> 4) * 4 + r;
        if (lr >= Me) continue;
        long long ci = cOff + (long long)lr * ldc + col;
        float v = ((float*)&acc[mi][nj])[r];
        if (outmode == 0) C[ci] = v;
        else C[ci] += v;
      }
    }
  }
}

// ---------------- attention QK^T (gload_lds + swizzle, causal skip) ----------
__global__ __launch_bounds__(256)
void k_qk3(const ushort_t* __restrict__ qh, const ushort_t* __restrict__ ql,
           const ushort_t* __restrict__ kh, const ushort_t* __restrict__ kl,
           float* __restrict__ sc) {
  __shared__ alignas(16) short Ash[128 * 64];
  __shared__ alignas(16) short Asl[128 * 64];
  __shared__ alignas(16) short Bsh[128 * 64];
  __shared__ alignas(16) short Bsl[128 * 64];
  int zl = blockIdx.z;
  int b = zl >> 4, hh = zl & 15, kv = hh >> 2;
  int m0 = blockIdx.x * 128, n0 = blockIdx.y * 128;
  if (n0 > m0 + 127) return;
  long long aBase = ((long long)(b * Sq) * Hq + hh) * HDq;
  long long bBase = ((long long)(b * Sq) * KVq + kv) * HDq;
  int t = threadIdx.x, w = t >> 6, lane = t & 63;
  int wm = w >> 1, wn = w & 1;
  int rA = lane >> 3;
  int sOff = ((lane & 7) ^ rA) << 3;
  f32x4 acc[4][4];
  #pragma unroll
  for (int i = 0; i < 4; ++i)
    #pragma unroll
    for (int j = 0; j < 4; ++j) { acc[i][j].x = 0.f; acc[i][j].y = 0.f; acc[i][j].z = 0.f; acc[i][j].w = 0.f; }
  {
    #pragma unroll
    for (int i = 0; i < 4; ++i) {
      int j = (w << 2) + i;
      int row = (j << 3) + rA;
      long long ao = aBase + (long long)(m0 + row) * (Hq * HDq) + sOff;
      long long bo = bBase + (long long)(n0 + row) * (KVq * HDq) + sOff;
      gload16(qh + ao, &Ash[j * 512]);
      gload16(ql + ao, &Asl[j * 512]);
      gload16(kh + bo, &Bsh[j * 512]);
      gload16(kl + bo, &Bsl[j * 512]);
    }
    __syncthreads();
    #pragma unroll
    for (int kk = 0; kk < 2; ++kk) {
      short8 afh[4], afl[4], bfh[4], bfl[4];
      int cl = (kk << 2) + (lane >> 4);
      #pragma unroll
      for (int mi = 0; mi < 4; ++mi) {
        int row = (wm << 6) + (mi << 4) + (lane & 15);
        int idx = (row << 6) + ((cl ^ (row & 7)) << 3);
        afh[mi] = *(const short8*)&Ash[idx];
        afl[mi] = *(const short8*)&Asl[idx];
      }
      #pragma unroll
      for (int nj = 0; nj < 4; ++nj) {
        int row = (wn << 6) + (nj << 4) + (lane & 15);
        int idx = (row << 6) + ((cl ^ (row & 7)) << 3);
        bfh[nj] = *(const short8*)&Bsh[idx];
        bfl[nj] = *(const short8*)&Bsl[idx];
      }
      #pragma unroll
      for (int mi = 0; mi < 4; ++mi)
        #pragma unroll
        for (int nj = 0; nj < 4; ++nj) {
          acc[mi][nj] = __builtin_amdgcn_mfma_f32_16x16x32_bf16(afh[mi], bfh[nj], acc[mi][nj], 0, 0, 0);
          acc[mi][nj] = __builtin_amdgcn_mfma_f32_16x16x32_bf16(afl[mi], bfh[nj], acc[mi][nj], 0, 0, 0);
          acc[mi][nj] = __builtin_amdgcn_mfma_f32_16x16x32_bf16(afh[mi], bfl[nj], acc[mi][nj], 0, 0, 0);
        }
    }
  }
  float* out = sc + (long long)zl * Sq * Sq;
  #pragma unroll
  for (int mi = 0; mi < 4; ++mi) {
    #pragma unroll
    for (int nj = 0; nj < 4; ++nj) {
      int col = n0 + (wn << 6) + (nj << 4) + (lane & 15);
      #pragma unroll
      for (int r = 0; r < 4; ++r) {
        int lr = m0 + (wm << 6) + (mi << 4) + (lane >> 4) * 4 + r;
        out[(long long)lr * Sq + col] = ((float*)&acc[mi][nj])[r] * 0.125f;
      }
    }
  }
}

// causal softmax; reads f32 sc (32 heads), writes P hi/lo bf16
__global__ __launch_bounds__(256)
void k_softmax3(const float* __restrict__ sc, ushort_t* __restrict__ ph,
                ushort_t* __restrict__ pl) {
  int row = blockIdx.x * 4 + (threadIdx.x >> 6);
  int lane = threadIdx.x & 63;
  int qi = row & (Sq - 1);
  const float* p = sc + (long long)row * Sq;
  float vals[16];
  float mx = -3.0e38f;
  #pragma unroll
  for (int j = 0; j < 16; j++) {
    int idx = lane + j * 64;
    float v = (idx <= qi) ? p[idx] : -3.0e38f;
    vals[j] = v;
    mx = fmaxf(mx, v);
  }
  #pragma unroll
  for (int o = 32; o > 0; o >>= 1) mx = fmaxf(mx, __shfl_xor(mx, o));
  float sum = 0.0f;
  #pragma unroll
  for (int j = 0; j < 16; j++) {
    int idx = lane + j * 64;
    float e = (idx <= qi) ? expf(vals[j] - mx) : 0.0f;
    vals[j] = e;
    sum += e;
  }
  #pragma unroll
  for (int o = 32; o > 0; o >>= 1) sum += __shfl_xor(sum, o);
  float inv = 1.0f / sum;
  long long base = (long long)row * Sq;
  #pragma unroll
  for (int j = 0; j < 16; j++) {
    int idx = lane + j * 64;
    float pr = vals[j] * inv;
    ushort_t hi = f2b(pr);
    ph[base + idx] = hi;
    pl[base + idx] = f2b(pr - b2f(hi));
  }
}

// attention PV (gload_lds + swizzle, triangular K bound). grid (8, 1, 32).
__global__ __launch_bounds__(256)
void k_pv3(const ushort_t* __restrict__ ph, const ushort_t* __restrict__ pl,
           const ushort_t* __restrict__ vth, const ushort_t* __restrict__ vtl,
           ushort_t* __restrict__ ath, ushort_t* __restrict__ atl) {
  __shared__ alignas(16) short Ash[128 * 64];
  __shared__ alignas(16) short Asl[128 * 64];
  __shared__ alignas(16) short Bsh[128 * 64];
  __shared__ alignas(16) short Bsl[128 * 64];
  int zl = blockIdx.z;
  int b = zl >> 4, hh = zl & 15, kv = hh >> 2;
  int m0 = blockIdx.x * 128;
  const ushort_t* Abh = ph + (long long)zl * Sq * Sq;
  const ushort_t* Abl = pl + (long long)zl * Sq * Sq;
  const ushort_t* Bbh = vth + (long long)((b * KVq + kv) * HDq) * Sq;
  const ushort_t* Bbl = vtl + (long long)((b * KVq + kv) * HDq) * Sq;
  int t = threadIdx.x, w = t >> 6, lane = t & 63;
  int wm = w >> 1, wn = w & 1;
  int rA = lane >> 3;
  int sOff = ((lane & 7) ^ rA) << 3;
  f32x4 acc[4][4];
  #pragma unroll
  for (int i = 0; i < 4; ++i)
    #pragma unroll
    for (int j = 0; j < 4; ++j) { acc[i][j].x = 0.f; acc[i][j].y = 0.f; acc[i][j].z = 0.f; acc[i][j].w = 0.f; }
  int ktmax = 2 * blockIdx.x + 2;
  for (int kt = 0; kt < ktmax; ++kt) {
    int k0 = kt << 6;
    #pragma unroll
    for (int i = 0; i < 4; ++i) {
      int j = (w << 2) + i;
      int row = (j << 3) + rA;
      long long ao = (long long)(m0 + row) * Sq + k0 + sOff;
      long long bo = (long long)(row & 63) * Sq + k0 + sOff;
      gload16(Abh + ao, &Ash[j * 512]);
      gload16(Abl + ao, &Asl[j * 512]);
      gload16(Bbh + bo, &Bsh[j * 512]);
      gload16(Bbl + bo, &Bsl[j * 512]);
    }
    __syncthreads();
    #pragma unroll
    for (int kk = 0; kk < 2; ++kk) {
      short8 afh[4], afl[4], bfh[4], bfl[4];
      int cl = (kk << 2) + (lane >> 4);
      #pragma unroll
      for (int mi = 0; mi < 4; ++mi) {
        int row = (wm << 6) + (mi << 4) + (lane & 15);
        int idx = (row << 6) + ((cl ^ (row & 7)) << 3);
        afh[mi] = *(const short8*)&Ash[idx];
        afl[mi] = *(const short8*)&Asl[idx];
      }
      #pragma unroll
      for (int nj = 0; nj < 4; ++nj) {
        int row = (wn << 6) + (nj << 4) + (lane & 15);
        int idx = (row << 6) + ((cl ^ (row & 7)) << 3);
        bfh[nj] = *(const short8*)&Bsh[idx];
        bfl[nj] = *(const short8*)&Bsl[idx];
      }
      #pragma unroll
      for (int mi = 0; mi < 4; ++mi)
        #pragma unroll
        for (int nj = 0; nj < 4; ++nj) {
          acc[mi][nj] = __builtin_amdgcn_mfma_f32_16x16x32_bf16(afh[mi], bfh[nj], acc[mi][nj], 0, 0, 0);
          acc[mi][nj] = __builtin_amdgcn_mfma_f32_16x16x32_bf16(afl[mi], bfh[nj], acc[mi][nj], 0, 0, 0);
          acc[mi][nj] = __builtin_amdgcn_mfma_f32_16x16x32_bf16(afh[mi], bfl[nj], acc[mi][nj], 0, 0, 0);
        }
    }
    __syncthreads();
  }
  #pragma unroll
  for (int mi = 0; mi < 4; ++mi) {
    #pragma unroll
    for (int nj = 0; nj < 4; ++nj) {
      int col = (wn << 6) + (nj << 4) + (lane & 15);
      if (col >= HDq) continue;
      #pragma unroll
      for (int r = 0; r < 4; ++r) {
        int lr = m0 + (wm << 6) + (mi << 4) + (lane >> 4) * 4 + r;
        long long ci = ((long long)(b * Sq + lr)) * (Hq * HDq) + hh * HDq + col;
        float v = ((float*)&acc[mi][nj])[r];
        ushort_t hi = f2b(v);
        ath[ci] = hi;
        atl[ci] = f2b(v - b2f(hi));
      }
    }
  }
}

// ---------------- MoE routing ----------------
__global__ void k_gate(const ushort_t* __restrict__ xh, const ushort_t* __restrict__ xl,
                       const float* __restrict__ gw, float* __restrict__ logits) {
  int n = blockIdx.x * 4 + (threadIdx.x >> 6);
  int lane = threadIdx.x & 63;
  float acc[Eq];
  #pragma unroll
  for (int e = 0; e < Eq; e++) acc[e] = 0.0f;
  for (int d = lane; d < Dq; d += 64) {
    size_t idx = (size_t)n * Dq + d;
    float xv = b2f(xh[idx]) + b2f(xl[idx]);
    const float* g = gw + (size_t)d * Eq;
    #pragma unroll
    for (int e = 0; e < Eq; e++) acc[e] += xv * g[e];
  }
  #pragma unroll
  for (int o = 32; o > 0; o >>= 1)
    #pragma unroll
    for (int e = 0; e < Eq; e++) acc[e] += __shfl_xor(acc[e], o);
  if (lane == 0) {
    #pragma unroll
    for (int e = 0; e < Eq; e++) logits[(size_t)n * Eq + e] = acc[e];
  }
}

__global__ void k_zero_counts(int* c) { if (threadIdx.x < 16) c[threadIdx.x] = 0; }

__global__ void k_route_count(const float* __restrict__ logits, float* __restrict__ topw,
                              int* __restrict__ sel, int* __restrict__ counts) {
  int n = blockIdx.x * blockDim.x + threadIdx.x;
  if (n >= Nq) return;
  const float* lg = logits + (size_t)n * Eq;
  int i1 = 0; float v1 = lg[0];
  #pragma unroll
  for (int e = 1; e < Eq; e++) if (lg[e] > v1) { v1 = lg[e]; i1 = e; }
  int i2 = -1; float v2 = -3.0e38f;
  #pragma unroll
  for (int e = 0; e < Eq; e++) if (e != i1 && lg[e] > v2) { v2 = lg[e]; i2 = e; }
  float e2 = expf(v2 - v1);
  float s = 1.0f + e2;
  topw[n * 2 + 0] = 1.0f / s;
  topw[n * 2 + 1] = e2 / s;
  sel[n * 2 + 0] = i1;
  sel[n * 2 + 1] = i2;
  atomicAdd(&counts[i1], 1);
  atomicAdd(&counts[i2], 1);
}

__global__ void k_scan(const int* __restrict__ counts, int* __restrict__ bases,
                       int* __restrict__ counts2) {
  if (threadIdx.x == 0) {
    int s = 0;
    for (int e = 0; e < Eq; e++) { bases[e] = s; s += counts[e]; counts2[e] = 0; }
  }
}

__global__ void k_route_assign(const int* __restrict__ sel, int* __restrict__ counts2,
                               const int* __restrict__ bases, int* __restrict__ row2tok,
                               int* __restrict__ posof) {
  int n = blockIdx.x * blockDim.x + threadIdx.x;
  if (n >= Nq) return;
  #pragma unroll
  for (int slot = 0; slot < TOPK; slot++) {
    int e = sel[n * 2 + slot];
    int pos = atomicAdd(&counts2[e], 1);
    int row = bases[e] + pos;
    row2tok[row] = n;
    posof[n * 2 + slot] = row;
  }
}

__global__ void k_gather_us(const ushort_t* __restrict__ xh, const ushort_t* __restrict__ xl,
                            const int* __restrict__ row2tok,
                            ushort_t* __restrict__ xgh, ushort_t* __restrict__ xgl) {
  int row = blockIdx.x;
  int tok = row2tok[row];
  int t = threadIdx.x;
  const uint2* sh = (const uint2*)(xh + (size_t)tok * Dq);
  const uint2* sl = (const uint2*)(xl + (size_t)tok * Dq);
  ((uint2*)(xgh + (size_t)row * Dq))[t] = sh[t];
  ((uint2*)(xgl + (size_t)row * Dq))[t] = sl[t];
}

__global__ void k_silumul3(const float* __restrict__ h13, const float* __restrict__ h3,
                           ushort_t* __restrict__ oh, ushort_t* __restrict__ ol) {
  long total = (long)MROW * Fq;
  long i = (long)blockIdx.x * blockDim.x + threadIdx.x;
  long st = (long)gridDim.x * blockDim.x;
  for (; i < total; i += st) {
    float a = h13[i];
    float s = (a / (1.0f + expf(-a))) * h3[i];
    ushort_t hi = f2b(s);
    oh[i] = hi;
    ol[i] = f2b(s - b2f(hi));
  }
}

__global__ void k_moe_combine(float* __restrict__ h, const float* __restrict__ y,
                              const float* __restrict__ topw, const int* __restrict__ posof) {
  int n = blockIdx.x;
  int t = threadIdx.x;
  float w0 = topw[n * 2 + 0], w1 = topw[n * 2 + 1];
  int r0 = posof[n * 2 + 0], r1 = posof[n * 2 + 1];
  float4 a = ((const float4*)(y + (size_t)r0 * Dq))[t];
  float4 b = ((const float4*)(y + (size_t)r1 * Dq))[t];
  float4 hv = ((float4*)(h + (size_t)n * Dq))[t];
  hv.x += w0 * a.x + w1 * b.x;
  hv.y += w0 * a.y + w1 * b.y;
  hv.z += w0 * a.z + w1 * b.z;
  hv.w += w0 * a.w + w1 * b.w;
  ((float4*)(h + (size_t)n * Dq))[t] = hv;
}

// ---------------- launch ----------------
extern "C" void kernel_launch(void* const* d_in, const int* in_sizes, int n_in,
                              void* d_out, int out_size, void* d_ws, size_t ws_size,
                              hipStream_t stream) {
  const int* ids       = (const int*)d_in[0];
  const int* pos       = (const int*)d_in[1];
  const float* tok_emb = (const float*)d_in[2];
  const float* attn_nw = (const float*)d_in[3];
  const float* ffn_nw  = (const float*)d_in[4];
  const float* wq      = (const float*)d_in[5];
  const float* wk      = (const float*)d_in[6];
  const float* wv      = (const float*)d_in[7];
  const float* wo      = (const float*)d_in[8];
  const float* gate    = (const float*)d_in[9];
  const float* w1      = (const float*)d_in[10];
  const float* w2      = (const float*)d_in[11];
  const float* w3      = (const float*)d_in[12];
  const float* fnw     = (const float*)d_in[13];
  const float* outw    = (const float*)d_in[14];
  float* out = (float*)d_out;
  float* ws = (float*)d_ws;
  float* dws = out;   // phase scratch inside d_out (62.5 MF; fully rewritten by LM head)

  float* h      = ws + O_H;
  ushort_t* xh  = (ushort_t*)(ws + O_XH);
  ushort_t* xl  = (ushort_t*)(ws + O_XL);
  float* qkv    = ws + O_QKV;
  ushort_t* ath = (ushort_t*)(ws + O_ATH);
  ushort_t* atl = (ushort_t*)(ws + O_ATL);
  ushort_t* qhB = (ushort_t*)(ws + O_QH);
  ushort_t* qlB = (ushort_t*)(ws + O_QL);
  ushort_t* khB = (ushort_t*)(ws + O_KH);
  ushort_t* klB = (ushort_t*)(ws + O_KL);
  ushort_t* vth = (ushort_t*)(ws + O_VTH);
  ushort_t* vtl = (ushort_t*)(ws + O_VTL);
  float* cosT   = ws + O_COS;
  float* sinT   = ws + O_SIN;
  float* logits = ws + O_LOG;
  float* topw   = ws + O_TPW;
  ushort_t* wTh = (ushort_t*)(ws + O_WTH);
  ushort_t* wTl = (ushort_t*)(ws + O_WTL);
  float* sc     = dws;                          // 32 heads f32 scores (32MF)
  ushort_t* ph  = (ushort_t*)(dws + 32*MF);     // P hi (16MF)
  ushort_t* pl  = (ushort_t*)(ws + O_SC);       // P lo (16MF, ws dead region)
  ushort_t* wQh = (ushort_t*)dws;               // QKV weight hi (consumed pre-qk3)
  ushort_t* wQl = (ushort_t*)(dws + MF);
  ushort_t* xgh = (ushort_t*)(ws + O_XGH);
  ushort_t* xgl = (ushort_t*)(ws + O_XGL);
  ushort_t* wAh = (ushort_t*)dws;               // expert weight hi (8MF)
  ushort_t* wAl = (ushort_t*)(dws + 8*MF);      // expert weight lo
  float* h13    = ws + O_H13;
  float* h3     = ws + O_H3;
  ushort_t* h13h= (ushort_t*)(ws + O_H13H);
  ushort_t* h13l= (ushort_t*)(ws + O_H13L);
  float* y      = ws + O_Y;
  ushort_t* owTh= (ushort_t*)(ws + O_SC);       // LM weight hi
  int* ip = (int*)(ws + O_INT);
  int* counts  = ip;
  int* counts2 = ip + 8;
  int* bases   = ip + 16;
  int* sel     = ip + 32;
  int* row2tok = ip + 32 + 4096;
  int* posof   = ip + 32 + 8192;

  k_rope_table<<<128, 256, 0, stream>>>(pos, cosT, sinT);
  k_embed<<<Nq, 256, 0, stream>>>(ids, tok_emb, h);

  for (int l = 0; l < Lq; l++) {
    // ---- attention ----
    k_rmsnorm3<<<Nq, 256, 0, stream>>>(h, attn_nw + (size_t)l * Dq, xh, xl);
    k_convT2<<<dim3(32, 32, 1), 256, 0, stream>>>(wq + (long long)l*Dq*Hq*HDq, wQh, wQl, Hq*HDq, Dq, 1, 0, 0, 0);
    k_convT2<<<dim3(8, 32, 1), 256, 0, stream>>>(wk + (long long)l*Dq*KVq*HDq, wQh + (size_t)1024*1024, wQl + (size_t)1024*1024, KVq*HDq, Dq, 1, 0, 0, 0);
    k_convT2<<<dim3(8, 32, 1), 256, 0, stream>>>(wv + (long long)l*Dq*KVq*HDq, wQh + (size_t)1280*1024, wQl + (size_t)1280*1024, KVq*HDq, Dq, 1, 0, 0, 0);
    k_mgemm3<<<dim3(16, 12, 1), 256, 0, stream>>>(xh, xl, wQh, wQl, qkv, 1536, Dq, Dq, 1536, 0, 0, nullptr, nullptr, Nq);
    k_rope3<<<(Nq * 20 * 32) / 256, 256, 0, stream>>>(qkv, cosT, sinT, qhB, qlB, khB, klB);
    k_convT2<<<dim3(2, 32, Bq*KVq), 256, 0, stream>>>(qkv + 1280, vth, vtl, 1536, Sq,
           KVq, (long long)Sq*1536, HDq, (long long)HDq*Sq);
    k_qk3<<<dim3(8, 8, 32), 256, 0, stream>>>(qhB, qlB, khB, klB, sc);
    k_softmax3<<<(32 * Sq) / 4, 256, 0, stream>>>(sc, ph, pl);
    k_pv3<<<dim3(8, 1, 32), 256, 0, stream>>>(ph, pl, vth, vtl, ath, atl);
    k_convT2<<<dim3(32, 32, 1), 256, 0, stream>>>(wo + (long long)l*Hq*HDq*Dq, wTh, wTl, Dq, Hq*HDq, 1, 0, 0, 0);
    k_mgemm3<<<dim3(16, 8, 1), 256, 0, stream>>>(ath, atl, wTh, wTl, h, Dq, Hq*HDq, Hq*HDq, Dq, 1, 0, nullptr, nullptr, Nq);

    // ---- MoE ----
    k_rmsnorm3<<<Nq, 256, 0, stream>>>(h, ffn_nw + (size_t)l * Dq, xh, xl);
    k_gate<<<Nq / 4, 256, 0, stream>>>(xh, xl, gate + (size_t)l * Dq * Eq, logits);
    k_zero_counts<<<1, 32, 0, stream>>>(counts);
    k_route_count<<<Nq / 256, 256, 0, stream>>>(logits, topw, sel, counts);
    k_scan<<<1, 1, 0, stream>>>(counts, bases, counts2);
    k_route_assign<<<Nq / 256, 256, 0, stream>>>(sel, counts2, bases, row2tok, posof);
    k_gather_us<<<MROW, 256, 0, stream>>>(xh, xl, row2tok, xgh, xgl);
    int last = (l == Lq - 1);   // no routing downstream of last MoE -> 1-pass bf16
    // w1
    k_convT2<<<dim3(64, 32, 8), 256, 0, stream>>>(w1 + (long long)l*Eq*Dq*Fq, wAh, last ? nullptr : wAl, Fq, Dq, 1, (long long)Dq*Fq, 0, (long long)Fq*Dq);
    if (last) k_mgemm1<<<dim3(16, 16, 8), 256, 0, stream>>>(xgh, wAh, h13, Fq, Dq, Dq, Fq, 0, 1, bases, counts, 0);
    else      k_mgemm3<<<dim3(16, 16, 8), 256, 0, stream>>>(xgh, xgl, wAh, wAl, h13, Fq, Dq, Dq, Fq, 0, 1, bases, counts, 0);
    // w3
    k_convT2<<<dim3(64, 32, 8), 256, 0, stream>>>(w3 + (long long)l*Eq*Dq*Fq, wAh, last ? nullptr : wAl, Fq, Dq, 1, (long long)Dq*Fq, 0, (long long)Fq*Dq);
    if (last) k_mgemm1<<<dim3(16, 16, 8), 256, 0, stream>>>(xgh, wAh, h3, Fq, Dq, Dq, Fq, 0, 1, bases, counts, 0);
    else      k_mgemm3<<<dim3(16, 16, 8), 256, 0, stream>>>(xgh, xgl, wAh, wAl, h3, Fq, Dq, Dq, Fq, 0, 1, bases, counts, 0);
    k_silumul3<<<4096, 256, 0, stream>>>(h13, h3, h13h, h13l);
    // w2
    k_convT2<<<dim3(32, 64, 8), 256, 0, stream>>>(w2 + (long long)l*Eq*Fq*Dq, wAh, last ? nullptr : wAl, Dq, Fq, 1, (long long)Fq*Dq, 0, (long long)Dq*Fq);
    if (last) k_mgemm1<<<dim3(16, 8, 8), 256, 0, stream>>>(h13h, wAh, y, Dq, Fq, Fq, Dq, 0, 1, bases, counts, 0);
    else      k_mgemm3<<<dim3(16, 8, 8), 256, 0, stream>>>(h13h, h13l, wAh, wAl, y, Dq, Fq, Fq, Dq, 0, 1, bases, counts, 0);
    k_moe_combine<<<Nq, 256, 0, stream>>>(h, y, topw, posof);
  }

  // ---- final norm + LM head (1-pass bf16, 128x128, gload_lds) ----
  k_rmsnorm3<<<Nq, 256, 0, stream>>>(h, fnw, xh, xl);
  k_convT2<<<dim3(1000, 32, 1), 256, 0, stream>>>(outw, owTh, nullptr, Vq, Dq, 1, 0, 0, 0);
  k_mgemm1<<<dim3(16, 250, 1), 256, 0, stream>>>(xh, owTh, out, Vq, Dq, Dq, Vq, 0, 0, nullptr, nullptr, Nq);
}

// Round 13
// 1475.083 us; speedup vs baseline: 1.5599x; 1.2402x over previous
//
#include <hip/hip_runtime.h>
#include <math.h>

typedef unsigned short ushort_t;
typedef __attribute__((ext_vector_type(8))) short short8;
typedef __attribute__((ext_vector_type(4))) float f32x4;

// ---------------- problem constants ----------------
#define Bq 2
#define Sq 1024
#define Dq 1024
#define Lq 2
#define HDq 64
#define Hq 16
#define KVq 4
#define Fq 2048
#define Eq 8
#define TOPK 2
#define Vq 32000
#define Nq (Bq*Sq)
#define EPSq 1e-5f
#define MROW (Nq*TOPK)

__device__ __forceinline__ float b2f(ushort_t u) {
  return __uint_as_float(((unsigned int)u) << 16);
}
__device__ __forceinline__ ushort_t f2b(float f) {
  unsigned int u = __float_as_uint(f);
  u += 0x7fffu + ((u >> 16) & 1u);   // RNE
  return (ushort_t)(u >> 16);
}

// async global->LDS (16B per lane)
typedef const void __attribute__((address_space(1)))* gas_cptr;
typedef void __attribute__((address_space(3)))* las_ptr;
__device__ __forceinline__ void gload16(const void* g, void* l) {
  __builtin_amdgcn_global_load_lds((gas_cptr)g, (las_ptr)l, 16, 0, 0);
}

// bijective XCD-aware swizzle of the (x,y) block plane (m204 formula)
__device__ __forceinline__ void xcd_tiles(int &bx, int &by) {
  int gx = gridDim.x;
  int nwg = gx * gridDim.y;
  int bid = blockIdx.y * gx + blockIdx.x;
  int q8 = nwg >> 3, r8 = nwg & 7;
  int xcd = bid & 7, idx = bid >> 3;
  int swz = (xcd < r8) ? xcd * (q8 + 1) + idx
                       : r8 * (q8 + 1) + (xcd - r8) * q8 + idx;
  bx = swz % gx;
  by = swz / gx;
}

// ---------------- workspace layout (float offsets) ----------------
#define MF ((size_t)1024*1024)
#define O_H    ((size_t)0)
#define O_XH   (2*MF)
#define O_XL   (3*MF)
#define O_QKV  (4*MF)
#define O_ATH  (7*MF)
#define O_ATL  (8*MF)
#define O_QH   (9*MF)
#define O_QL   (10*MF)
#define O_KH   (11*MF)
#define O_KL   (11*MF + MF/4)
#define O_VTH  (11*MF + MF/2)
#define O_VTL  (11*MF + 3*MF/4)
#define O_COS  (12*MF)
#define O_SIN  (O_COS + 32768)
#define O_LOG  (O_SIN + 32768)
#define O_TPW  (O_LOG + 16384)
#define O_WTH  (O_COS + MF/8)
#define O_WTL  (O_WTH + MF/2)
#define O_SC   (27*MF/2)              // P lo (attn) / MoE hb / LM weight
// MoE overlays:
#define O_XGH  (4*MF)
#define O_XGL  (6*MF)
#define O_HB   (O_SC)                 // combined [MROW][4096] f32 (16MF)
#define O_H13H (O_SC + 16*MF)
#define O_H13L (O_SC + 20*MF)
#define O_Y    (O_SC + 24*MF)
#define O_INT  (42*MF)

// ---------------- small kernels ----------------

__global__ void k_rope_table(const int* __restrict__ pos, float* __restrict__ cosT,
                             float* __restrict__ sinT) {
  int i = blockIdx.x * blockDim.x + threadIdx.x;
  if (i >= Sq * 32) return;
  int s = i >> 5, f = i & 31;
  float freq = 1.0f / powf(1.0e6f, (float)f / 32.0f);
  float ang = (float)pos[s] * freq;
  cosT[i] = cosf(ang);
  sinT[i] = sinf(ang);
}

__global__ void k_embed(const int* __restrict__ ids, const float* __restrict__ emb,
                        float* __restrict__ h) {
  int n = blockIdx.x;
  const float4* src = (const float4*)(emb + (size_t)ids[n] * Dq);
  float4* dst = (float4*)(h + (size_t)n * Dq);
  dst[threadIdx.x] = src[threadIdx.x];
}

__global__ void k_rmsnorm3(const float* __restrict__ in, const float* __restrict__ w,
                           ushort_t* __restrict__ outh, ushort_t* __restrict__ outl) {
  int n = blockIdx.x;
  int t = threadIdx.x;
  float4 v = ((const float4*)(in + (size_t)n * Dq))[t];
  float ss = v.x*v.x + v.y*v.y + v.z*v.z + v.w*v.w;
  #pragma unroll
  for (int o = 32; o > 0; o >>= 1) ss += __shfl_down(ss, o);
  __shared__ float red[4];
  if ((t & 63) == 0) red[t >> 6] = ss;
  __syncthreads();
  float tot = red[0] + red[1] + red[2] + red[3];
  float r = rsqrtf(tot / (float)Dq + EPSq);
  float4 wl = ((const float4*)w)[t];
  float o4[4];
  o4[0] = v.x * r * wl.x; o4[1] = v.y * r * wl.y;
  o4[2] = v.z * r * wl.z; o4[3] = v.w * r * wl.w;
  ushort_t* oh = outh + (size_t)n * Dq + t * 4;
  ushort_t* ol = outl + (size_t)n * Dq + t * 4;
  #pragma unroll
  for (int j = 0; j < 4; j++) {
    ushort_t hi = f2b(o4[j]);
    oh[j] = hi;
    ol[j] = f2b(o4[j] - b2f(hi));
  }
}

// fused rope + hi/lo split from combined qkv buffer (row stride 1536)
__global__ void k_rope3(const float* __restrict__ qkv, const float* __restrict__ cosT,
                        const float* __restrict__ sinT,
                        ushort_t* __restrict__ qh, ushort_t* __restrict__ ql,
                        ushort_t* __restrict__ kh, ushort_t* __restrict__ kl) {
  int i = blockIdx.x * blockDim.x + threadIdx.x;
  int n = i / 640, r = i % 640;
  int hh = r >> 5, f = r & 31;
  int s = n & (Sq - 1);
  float c = cosT[s * 32 + f], sn = sinT[s * 32 + f];
  int srcCol = (hh < 16) ? hh * 64 + 2 * f : 1024 + (hh - 16) * 64 + 2 * f;
  const float* pp = qkv + (size_t)n * 1536 + srcCol;
  float xe = pp[0], xo = pp[1];
  float re = xe * c - xo * sn;
  float im = xe * sn + xo * c;
  ushort_t reh = f2b(re), imh = f2b(im);
  ushort_t rel = f2b(re - b2f(reh)), iml = f2b(im - b2f(imh));
  if (hh < 16) {
    size_t d = (size_t)n * 1024 + hh * 64 + 2 * f;
    qh[d] = reh; qh[d + 1] = imh;
    ql[d] = rel; ql[d + 1] = iml;
  } else {
    size_t d = (size_t)n * 256 + (hh - 16) * 64 + 2 * f;
    kh[d] = reh; kh[d + 1] = imh;
    kl[d] = rel; kl[d + 1] = iml;
  }
}

// tiled transpose + f32->bf16 hi/lo split; dl==nullptr -> hi only
__global__ void k_convT2(const float* __restrict__ src, ushort_t* __restrict__ dh,
                         ushort_t* __restrict__ dl, int srcStride, int dstStride,
                         int zdiv, long long srcZa, long long srcZb, long long dstZ) {
  __shared__ float tile[32][33];
  int z = blockIdx.z;
  const float* s = src + (long long)(z / zdiv) * srcZa + (long long)(z % zdiv) * srcZb;
  int r0 = blockIdx.y * 32, c0 = blockIdx.x * 32;
  int tc = threadIdx.x & 31, tr = threadIdx.x >> 5;
  #pragma unroll
  for (int i = 0; i < 4; ++i)
    tile[tr + i * 8][tc] = s[(long long)(r0 + tr + i * 8) * srcStride + c0 + tc];
  __syncthreads();
  #pragma unroll
  for (int i = 0; i < 4; ++i) {
    float v = tile[tc][tr + i * 8];
    ushort_t hi = f2b(v);
    long long idx = (long long)z * dstZ + (long long)(c0 + tr + i * 8) * dstStride + r0 + tc;
    dh[idx] = hi;
    if (dl) dl[idx] = f2b(v - b2f(hi));
  }
}

// ---------------- fused bf16x3 MFMA GEMM (gload_lds + swizzle + XCD) ----------
__global__ __launch_bounds__(256)
void k_mgemm3(const ushort_t* __restrict__ Ah, const ushort_t* __restrict__ Al,
              const ushort_t* __restrict__ Bh, const ushort_t* __restrict__ Bl,
              float* __restrict__ C,
              int N, int Kd, int lda, int ldc,
              int outmode, int mode,
              const int* __restrict__ grpBase, const int* __restrict__ grpCnt, int M) {
  __shared__ alignas(16) short Ash[128 * 64];
  __shared__ alignas(16) short Asl[128 * 64];
  __shared__ alignas(16) short Bsh[128 * 64];
  __shared__ alignas(16) short Bsl[128 * 64];
  int z = blockIdx.z;
  const ushort_t *Abh, *Abl, *Bbh, *Bbl;
  long long cOff;
  int Me = M;
  if (mode == 1) {
    int base = grpBase[z];
    Me = grpCnt[z];
    Abh = Ah + (long long)base * lda;
    Abl = Al + (long long)base * lda;
    long long bo = (long long)z * ((long long)N * Kd);
    Bbh = Bh + bo; Bbl = Bl + bo;
    cOff = (long long)base * ldc;
  } else {
    Abh = Ah; Abl = Al; Bbh = Bh; Bbl = Bl; cOff = 0;
  }
  int bx, by;
  xcd_tiles(bx, by);
  int m0 = bx * 128, n0 = by * 128;
  if (m0 >= Me) return;
  int t = threadIdx.x, w = t >> 6, lane = t & 63;
  int wm = w >> 1, wn = w & 1;
  int rA = lane >> 3;
  int sOff = ((lane & 7) ^ rA) << 3;
  f32x4 acc[4][4];
  #pragma unroll
  for (int i = 0; i < 4; ++i)
    #pragma unroll
    for (int j = 0; j < 4; ++j) { acc[i][j].x = 0.f; acc[i][j].y = 0.f; acc[i][j].z = 0.f; acc[i][j].w = 0.f; }
  int nkt = Kd >> 6;
  for (int kt = 0; kt < nkt; ++kt) {
    int k0 = kt << 6;
    #pragma unroll
    for (int i = 0; i < 4; ++i) {
      int j = (w << 2) + i;
      int row = (j << 3) + rA;
      long long ao = (long long)(m0 + row) * lda + k0 + sOff;
      long long bo = (long long)(n0 + row) * Kd + k0 + sOff;
      gload16(Abh + ao, &Ash[j * 512]);
      gload16(Abl + ao, &Asl[j * 512]);
      gload16(Bbh + bo, &Bsh[j * 512]);
      gload16(Bbl + bo, &Bsl[j * 512]);
    }
    __syncthreads();
    #pragma unroll
    for (int kk = 0; kk < 2; ++kk) {
      short8 afh[4], afl[4], bfh[4], bfl[4];
      int cl = (kk << 2) + (lane >> 4);
      #pragma unroll
      for (int mi = 0; mi < 4; ++mi) {
        int row = (wm << 6) + (mi << 4) + (lane & 15);
        int idx = (row << 6) + ((cl ^ (row & 7)) << 3);
        afh[mi] = *(const short8*)&Ash[idx];
        afl[mi] = *(const short8*)&Asl[idx];
      }
      #pragma unroll
      for (int nj = 0; nj < 4; ++nj) {
        int row = (wn << 6) + (nj << 4) + (lane & 15);
        int idx = (row << 6) + ((cl ^ (row & 7)) << 3);
        bfh[nj] = *(const short8*)&Bsh[idx];
        bfl[nj] = *(const short8*)&Bsl[idx];
      }
      #pragma unroll
      for (int mi = 0; mi < 4; ++mi)
        #pragma unroll
        for (int nj = 0; nj < 4; ++nj) {
          acc[mi][nj] = __builtin_amdgcn_mfma_f32_16x16x32_bf16(afh[mi], bfh[nj], acc[mi][nj], 0, 0, 0);
          acc[mi][nj] = __builtin_amdgcn_mfma_f32_16x16x32_bf16(afl[mi], bfh[nj], acc[mi][nj], 0, 0, 0);
          acc[mi][nj] = __builtin_amdgcn_mfma_f32_16x16x32_bf16(afh[mi], bfl[nj], acc[mi][nj], 0, 0, 0);
        }
    }
    __syncthreads();
  }
  #pragma unroll
  for (int mi = 0; mi < 4; ++mi) {
    #pragma unroll
    for (int nj = 0; nj < 4; ++nj) {
      int col = n0 + (wn << 6) + (nj << 4) + (lane & 15);
      if (col >= N) continue;
      #pragma unroll
      for (int r = 0; r < 4; ++r) {
        int lr = m0 + (wm << 6) + (mi << 4) + (lane >> 4) * 4 + r;
        if (lr >= Me) continue;
        long long ci = cOff + (long long)lr * ldc + col;
        float v = ((float*)&acc[mi][nj])[r];
        if (outmode == 0) C[ci] = v;
        else C[ci] += v;
      }
    }
  }
}

// ---------------- 1-pass bf16 MFMA GEMM (gload_lds + swizzle + XCD) -----------
__global__ __launch_bounds__(256)
void k_mgemm1(const ushort_t* __restrict__ Ah, const ushort_t* __restrict__ Bh,
              float* __restrict__ C,
              int N, int Kd, int lda, int ldc,
              int outmode, int mode,
              const int* __restrict__ grpBase, const int* __restrict__ grpCnt, int M) {
  __shared__ alignas(16) short Ash[128 * 64];
  __shared__ alignas(16) short Bsh[128 * 64];
  int z = blockIdx.z;
  const ushort_t *Abh, *Bbh;
  long long cOff;
  int Me = M;
  if (mode == 1) {
    int base = grpBase[z];
    Me = grpCnt[z];
    Abh = Ah + (long long)base * lda;
    Bbh = Bh + (long long)z * ((long long)N * Kd);
    cOff = (long long)base * ldc;
  } else {
    Abh = Ah; Bbh = Bh; cOff = 0;
  }
  int bx, by;
  xcd_tiles(bx, by);
  int m0 = bx * 128, n0 = by * 128;
  if (m0 >= Me) return;
  int t = threadIdx.x, w = t >> 6, lane = t & 63;
  int wm = w >> 1, wn = w & 1;
  int rA = lane >> 3;
  int sOff = ((lane & 7) ^ rA) << 3;
  f32x4 acc[4][4];
  #pragma unroll
  for (int i = 0; i < 4; ++i)
    #pragma unroll
    for (int j = 0; j < 4; ++j) { acc[i][j].x = 0.f; acc[i][j].y = 0.f; acc[i][j].z = 0.f; acc[i][j].w = 0.f; }
  int nkt = Kd >> 6;
  for (int kt = 0; kt < nkt; ++kt) {
    int k0 = kt << 6;
    #pragma unroll
    for (int i = 0; i < 4; ++i) {
      int j = (w << 2) + i;
      int row = (j << 3) + rA;
      gload16(Abh + (long long)(m0 + row) * lda + k0 + sOff, &Ash[j * 512]);
      gload16(Bbh + (long long)(n0 + row) * Kd + k0 + sOff, &Bsh[j * 512]);
    }
    __syncthreads();
    #pragma unroll
    for (int kk = 0; kk < 2; ++kk) {
      short8 afh[4], bfh[4];
      int cl = (kk << 2) + (lane >> 4);
      #pragma unroll
      for (int mi = 0; mi < 4; ++mi) {
        int row = (wm << 6) + (mi << 4) + (lane & 15);
        afh[mi] = *(const short8*)&Ash[(row << 6) + ((cl ^ (row & 7)) << 3)];
      }
      #pragma unroll
      for (int nj = 0; nj < 4; ++nj) {
        int row = (wn << 6) + (nj << 4) + (lane & 15);
        bfh[nj] = *(const short8*)&Bsh[(row << 6) + ((cl ^ (row & 7)) << 3)];
      }
      #pragma unroll
      for (int mi = 0; mi < 4; ++mi)
        #pragma unroll
        for (int nj = 0; nj < 4; ++nj)
          acc[mi][nj] = __builtin_amdgcn_mfma_f32_16x16x32_bf16(afh[mi], bfh[nj], acc[mi][nj], 0, 0, 0);
    }
    __syncthreads();
  }
  #pragma unroll
  for (int mi = 0; mi < 4; ++mi) {
    #pragma unroll
    for (int nj = 0; nj < 4; ++nj) {
      int col = n0 + (wn << 6) + (nj << 4) + (lane & 15);
      if (col >= N) continue;
      #pragma unroll
      for (int r = 0; r < 4; ++r) {
        int lr = m0 + (wm << 6) + (mi << 4) + (lane >> 4) * 4 + r;
        if (lr >= Me) continue;
        long long ci = cOff + (long long)lr * ldc + col;
        float v = ((float*)&acc[mi][nj])[r];
        if (outmode == 0) C[ci] = v;
        else C[ci] += v;
      }
    }
  }
}

// ---------------- attention QK^T (gload_lds + swizzle, causal skip) ----------
__global__ __launch_bounds__(256)
void k_qk3(const ushort_t* __restrict__ qh, const ushort_t* __restrict__ ql,
           const ushort_t* __restrict__ kh, const ushort_t* __restrict__ kl,
           float* __restrict__ sc) {
  __shared__ alignas(16) short Ash[128 * 64];
  __shared__ alignas(16) short Asl[128 * 64];
  __shared__ alignas(16) short Bsh[128 * 64];
  __shared__ alignas(16) short Bsl[128 * 64];
  int zl = blockIdx.z;
  int b = zl >> 4, hh = zl & 15, kv = hh >> 2;
  int m0 = blockIdx.x * 128, n0 = blockIdx.y * 128;
  if (n0 > m0 + 127) return;
  long long aBase = ((long long)(b * Sq) * Hq + hh) * HDq;
  long long bBase = ((long long)(b * Sq) * KVq + kv) * HDq;
  int t = threadIdx.x, w = t >> 6, lane = t & 63;
  int wm = w >> 1, wn = w & 1;
  int rA = lane >> 3;
  int sOff = ((lane & 7) ^ rA) << 3;
  f32x4 acc[4][4];
  #pragma unroll
  for (int i = 0; i < 4; ++i)
    #pragma unroll
    for (int j = 0; j < 4; ++j) { acc[i][j].x = 0.f; acc[i][j].y = 0.f; acc[i][j].z = 0.f; acc[i][j].w = 0.f; }
  {
    #pragma unroll
    for (int i = 0; i < 4; ++i) {
      int j = (w << 2) + i;
      int row = (j << 3) + rA;
      long long ao = aBase + (long long)(m0 + row) * (Hq * HDq) + sOff;
      long long bo = bBase + (long long)(n0 + row) * (KVq * HDq) + sOff;
      gload16(qh + ao, &Ash[j * 512]);
      gload16(ql + ao, &Asl[j * 512]);
      gload16(kh + bo, &Bsh[j * 512]);
      gload16(kl + bo, &Bsl[j * 512]);
    }
    __syncthreads();
    #pragma unroll
    for (int kk = 0; kk < 2; ++kk) {
      short8 afh[4], afl[4], bfh[4], bfl[4];
      int cl = (kk << 2) + (lane >> 4);
      #pragma unroll
      for (int mi = 0; mi < 4; ++mi) {
        int row = (wm << 6) + (mi << 4) + (lane & 15);
        int idx = (row << 6) + ((cl ^ (row & 7)) << 3);
        afh[mi] = *(const short8*)&Ash[idx];
        afl[mi] = *(const short8*)&Asl[idx];
      }
      #pragma unroll
      for (int nj = 0; nj < 4; ++nj) {
        int row = (wn << 6) + (nj << 4) + (lane & 15);
        int idx = (row << 6) + ((cl ^ (row & 7)) << 3);
        bfh[nj] = *(const short8*)&Bsh[idx];
        bfl[nj] = *(const short8*)&Bsl[idx];
      }
      #pragma unroll
      for (int mi = 0; mi < 4; ++mi)
        #pragma unroll
        for (int nj = 0; nj < 4; ++nj) {
          acc[mi][nj] = __builtin_amdgcn_mfma_f32_16x16x32_bf16(afh[mi], bfh[nj], acc[mi][nj], 0, 0, 0);
          acc[mi][nj] = __builtin_amdgcn_mfma_f32_16x16x32_bf16(afl[mi], bfh[nj], acc[mi][nj], 0, 0, 0);
          acc[mi][nj] = __builtin_amdgcn_mfma_f32_16x16x32_bf16(afh[mi], bfl[nj], acc[mi][nj], 0, 0, 0);
        }
    }
  }
  float* out = sc + (long long)zl * Sq * Sq;
  #pragma unroll
  for (int mi = 0; mi < 4; ++mi) {
    #pragma unroll
    for (int nj = 0; nj < 4; ++nj) {
      int col = n0 + (wn << 6) + (nj << 4) + (lane & 15);
      #pragma unroll
      for (int r = 0; r < 4; ++r) {
        int lr = m0 + (wm << 6) + (mi << 4) + (lane >> 4) * 4 + r;
        out[(long long)lr * Sq + col] = ((float*)&acc[mi][nj])[r] * 0.125f;
      }
    }
  }
}

// causal softmax; reads f32 sc (32 heads), writes P hi/lo bf16
__global__ __launch_bounds__(256)
void k_softmax3(const float* __restrict__ sc, ushort_t* __restrict__ ph,
                ushort_t* __restrict__ pl) {
  int row = blockIdx.x * 4 + (threadIdx.x >> 6);
  int lane = threadIdx.x & 63;
  int qi = row & (Sq - 1);
  const float* p = sc + (long long)row * Sq;
  float vals[16];
  float mx = -3.0e38f;
  #pragma unroll
  for (int j = 0; j < 16; j++) {
    int idx = lane + j * 64;
    float v = (idx <= qi) ? p[idx] : -3.0e38f;
    vals[j] = v;
    mx = fmaxf(mx, v);
  }
  #pragma unroll
  for (int o = 32; o > 0; o >>= 1) mx = fmaxf(mx, __shfl_xor(mx, o));
  float sum = 0.0f;
  #pragma unroll
  for (int j = 0; j < 16; j++) {
    int idx = lane + j * 64;
    float e = (idx <= qi) ? expf(vals[j] - mx) : 0.0f;
    vals[j] = e;
    sum += e;
  }
  #pragma unroll
  for (int o = 32; o > 0; o >>= 1) sum += __shfl_xor(sum, o);
  float inv = 1.0f / sum;
  long long base = (long long)row * Sq;
  #pragma unroll
  for (int j = 0; j < 16; j++) {
    int idx = lane + j * 64;
    float pr = vals[j] * inv;
    ushort_t hi = f2b(pr);
    ph[base + idx] = hi;
    pl[base + idx] = f2b(pr - b2f(hi));
  }
}

// attention PV (gload_lds + swizzle, triangular K bound). grid (8, 1, 32).
__global__ __launch_bounds__(256)
void k_pv3(const ushort_t* __restrict__ ph, const ushort_t* __restrict__ pl,
           const ushort_t* __restrict__ vth, const ushort_t* __restrict__ vtl,
           ushort_t* __restrict__ ath, ushort_t* __restrict__ atl) {
  __shared__ alignas(16) short Ash[128 * 64];
  __shared__ alignas(16) short Asl[128 * 64];
  __shared__ alignas(16) short Bsh[128 * 64];
  __shared__ alignas(16) short Bsl[128 * 64];
  int zl = blockIdx.z;
  int b = zl >> 4, hh = zl & 15, kv = hh >> 2;
  int m0 = blockIdx.x * 128;
  const ushort_t* Abh = ph + (long long)zl * Sq * Sq;
  const ushort_t* Abl = pl + (long long)zl * Sq * Sq;
  const ushort_t* Bbh = vth + (long long)((b * KVq + kv) * HDq) * Sq;
  const ushort_t* Bbl = vtl + (long long)((b * KVq + kv) * HDq) * Sq;
  int t = threadIdx.x, w = t >> 6, lane = t & 63;
  int wm = w >> 1, wn = w & 1;
  int rA = lane >> 3;
  int sOff = ((lane & 7) ^ rA) << 3;
  f32x4 acc[4][4];
  #pragma unroll
  for (int i = 0; i < 4; ++i)
    #pragma unroll
    for (int j = 0; j < 4; ++j) { acc[i][j].x = 0.f; acc[i][j].y = 0.f; acc[i][j].z = 0.f; acc[i][j].w = 0.f; }
  int ktmax = 2 * blockIdx.x + 2;
  for (int kt = 0; kt < ktmax; ++kt) {
    int k0 = kt << 6;
    #pragma unroll
    for (int i = 0; i < 4; ++i) {
      int j = (w << 2) + i;
      int row = (j << 3) + rA;
      long long ao = (long long)(m0 + row) * Sq + k0 + sOff;
      long long bo = (long long)(row & 63) * Sq + k0 + sOff;
      gload16(Abh + ao, &Ash[j * 512]);
      gload16(Abl + ao, &Asl[j * 512]);
      gload16(Bbh + bo, &Bsh[j * 512]);
      gload16(Bbl + bo, &Bsl[j * 512]);
    }
    __syncthreads();
    #pragma unroll
    for (int kk = 0; kk < 2; ++kk) {
      short8 afh[4], afl[4], bfh[4], bfl[4];
      int cl = (kk << 2) + (lane >> 4);
      #pragma unroll
      for (int mi = 0; mi < 4; ++mi) {
        int row = (wm << 6) + (mi << 4) + (lane & 15);
        int idx = (row << 6) + ((cl ^ (row & 7)) << 3);
        afh[mi] = *(const short8*)&Ash[idx];
        afl[mi] = *(const short8*)&Asl[idx];
      }
      #pragma unroll
      for (int nj = 0; nj < 4; ++nj) {
        int row = (wn << 6) + (nj << 4) + (lane & 15);
        int idx = (row << 6) + ((cl ^ (row & 7)) << 3);
        bfh[nj] = *(const short8*)&Bsh[idx];
        bfl[nj] = *(const short8*)&Bsl[idx];
      }
      #pragma unroll
      for (int mi = 0; mi < 4; ++mi)
        #pragma unroll
        for (int nj = 0; nj < 4; ++nj) {
          acc[mi][nj] = __builtin_amdgcn_mfma_f32_16x16x32_bf16(afh[mi], bfh[nj], acc[mi][nj], 0, 0, 0);
          acc[mi][nj] = __builtin_amdgcn_mfma_f32_16x16x32_bf16(afl[mi], bfh[nj], acc[mi][nj], 0, 0, 0);
          acc[mi][nj] = __builtin_amdgcn_mfma_f32_16x16x32_bf16(afh[mi], bfl[nj], acc[mi][nj], 0, 0, 0);
        }
    }
    __syncthreads();
  }
  #pragma unroll
  for (int mi = 0; mi < 4; ++mi) {
    #pragma unroll
    for (int nj = 0; nj < 4; ++nj) {
      int col = (wn << 6) + (nj << 4) + (lane & 15);
      if (col >= HDq) continue;
      #pragma unroll
      for (int r = 0; r < 4; ++r) {
        int lr = m0 + (wm << 6) + (mi << 4) + (lane >> 4) * 4 + r;
        long long ci = ((long long)(b * Sq + lr)) * (Hq * HDq) + hh * HDq + col;
        float v = ((float*)&acc[mi][nj])[r];
        ushort_t hi = f2b(v);
        ath[ci] = hi;
        atl[ci] = f2b(v - b2f(hi));
      }
    }
  }
}

// ---------------- MoE routing ----------------
__global__ void k_gate(const ushort_t* __restrict__ xh, const ushort_t* __restrict__ xl,
                       const float* __restrict__ gw, float* __restrict__ logits) {
  int n = blockIdx.x * 4 + (threadIdx.x >> 6);
  int lane = threadIdx.x & 63;
  float acc[Eq];
  #pragma unroll
  for (int e = 0; e < Eq; e++) acc[e] = 0.0f;
  for (int d = lane; d < Dq; d += 64) {
    size_t idx = (size_t)n * Dq + d;
    float xv = b2f(xh[idx]) + b2f(xl[idx]);
    const float* g = gw + (size_t)d * Eq;
    #pragma unroll
    for (int e = 0; e < Eq; e++) acc[e] += xv * g[e];
  }
  #pragma unroll
  for (int o = 32; o > 0; o >>= 1)
    #pragma unroll
    for (int e = 0; e < Eq; e++) acc[e] += __shfl_xor(acc[e], o);
  if (lane == 0) {
    #pragma unroll
    for (int e = 0; e < Eq; e++) logits[(size_t)n * Eq + e] = acc[e];
  }
}

__global__ void k_zero_counts(int* c) { if (threadIdx.x < 16) c[threadIdx.x] = 0; }

__global__ void k_route_count(const float* __restrict__ logits, float* __restrict__ topw,
                              int* __restrict__ sel, int* __restrict__ counts) {
  int n = blockIdx.x * blockDim.x + threadIdx.x;
  if (n >= Nq) return;
  const float* lg = logits + (size_t)n * Eq;
  int i1 = 0; float v1 = lg[0];
  #pragma unroll
  for (int e = 1; e < Eq; e++) if (lg[e] > v1) { v1 = lg[e]; i1 = e; }
  int i2 = -1; float v2 = -3.0e38f;
  #pragma unroll
  for (int e = 0; e < Eq; e++) if (e != i1 && lg[e] > v2) { v2 = lg[e]; i2 = e; }
  float e2 = expf(v2 - v1);
  float s = 1.0f + e2;
  topw[n * 2 + 0] = 1.0f / s;
  topw[n * 2 + 1] = e2 / s;
  sel[n * 2 + 0] = i1;
  sel[n * 2 + 1] = i2;
  atomicAdd(&counts[i1], 1);
  atomicAdd(&counts[i2], 1);
}

__global__ void k_scan(const int* __restrict__ counts, int* __restrict__ bases,
                       int* __restrict__ counts2) {
  if (threadIdx.x == 0) {
    int s = 0;
    for (int e = 0; e < Eq; e++) { bases[e] = s; s += counts[e]; counts2[e] = 0; }
  }
}

__global__ void k_route_assign(const int* __restrict__ sel, int* __restrict__ counts2,
                               const int* __restrict__ bases, int* __restrict__ row2tok,
                               int* __restrict__ posof) {
  int n = blockIdx.x * blockDim.x + threadIdx.x;
  if (n >= Nq) return;
  #pragma unroll
  for (int slot = 0; slot < TOPK; slot++) {
    int e = sel[n * 2 + slot];
    int pos = atomicAdd(&counts2[e], 1);
    int row = bases[e] + pos;
    row2tok[row] = n;
    posof[n * 2 + slot] = row;
  }
}

__global__ void k_gather_us(const ushort_t* __restrict__ xh, const ushort_t* __restrict__ xl,
                            const int* __restrict__ row2tok,
                            ushort_t* __restrict__ xgh, ushort_t* __restrict__ xgl) {
  int row = blockIdx.x;
  int tok = row2tok[row];
  int t = threadIdx.x;
  const uint2* sh = (const uint2*)(xh + (size_t)tok * Dq);
  const uint2* sl = (const uint2*)(xl + (size_t)tok * Dq);
  ((uint2*)(xgh + (size_t)row * Dq))[t] = sh[t];
  ((uint2*)(xgl + (size_t)row * Dq))[t] = sl[t];
}

// silu(hb[:, :2048]) * hb[:, 2048:] -> hi/lo bf16
__global__ void k_silumul3b(const float* __restrict__ hb,
                            ushort_t* __restrict__ oh, ushort_t* __restrict__ ol) {
  long total = (long)MROW * Fq;
  long i = (long)blockIdx.x * blockDim.x + threadIdx.x;
  long st = (long)gridDim.x * blockDim.x;
  for (; i < total; i += st) {
    long r = i >> 11, f = i & 2047;
    float a = hb[(r << 12) + f];
    float b = hb[(r << 12) + 2048 + f];
    float s = (a / (1.0f + expf(-a))) * b;
    ushort_t hi = f2b(s);
    oh[i] = hi;
    ol[i] = f2b(s - b2f(hi));
  }
}

__global__ void k_moe_combine(float* __restrict__ h, const float* __restrict__ y,
                              const float* __restrict__ topw, const int* __restrict__ posof) {
  int n = blockIdx.x;
  int t = threadIdx.x;
  float w0 = topw[n * 2 + 0], w1 = topw[n * 2 + 1];
  int r0 = posof[n * 2 + 0], r1 = posof[n * 2 + 1];
  float4 a = ((const float4*)(y + (size_t)r0 * Dq))[t];
  float4 b = ((const float4*)(y + (size_t)r1 * Dq))[t];
  float4 hv = ((float4*)(h + (size_t)n * Dq))[t];
  hv.x += w0 * a.x + w1 * b.x;
  hv.y += w0 * a.y + w1 * b.y;
  hv.z += w0 * a.z + w1 * b.z;
  hv.w += w0 * a.w + w1 * b.w;
  ((float4*)(h + (size_t)n * Dq))[t] = hv;
}

// ---------------- launch ----------------
extern "C" void kernel_launch(void* const* d_in, const int* in_sizes, int n_in,
                              void* d_out, int out_size, void* d_ws, size_t ws_size,
                              hipStream_t stream) {
  const int* ids       = (const int*)d_in[0];
  const int* pos       = (const int*)d_in[1];
  const float* tok_emb = (const float*)d_in[2];
  const float* attn_nw = (const float*)d_in[3];
  const float* ffn_nw  = (const float*)d_in[4];
  const float* wq      = (const float*)d_in[5];
  const float* wk      = (const float*)d_in[6];
  const float* wv      = (const float*)d_in[7];
  const float* wo      = (const float*)d_in[8];
  const float* gate    = (const float*)d_in[9];
  const float* w1      = (const float*)d_in[10];
  const float* w2      = (const float*)d_in[11];
  const float* w3      = (const float*)d_in[12];
  const float* fnw     = (const float*)d_in[13];
  const float* outw    = (const float*)d_in[14];
  float* out = (float*)d_out;
  float* ws = (float*)d_ws;
  float* dws = out;   // phase scratch inside d_out (62.5 MF; fully rewritten by LM head)

  float* h      = ws + O_H;
  ushort_t* xh  = (ushort_t*)(ws + O_XH);
  ushort_t* xl  = (ushort_t*)(ws + O_XL);
  float* qkv    = ws + O_QKV;
  ushort_t* ath = (ushort_t*)(ws + O_ATH);
  ushort_t* atl = (ushort_t*)(ws + O_ATL);
  ushort_t* qhB = (ushort_t*)(ws + O_QH);
  ushort_t* qlB = (ushort_t*)(ws + O_QL);
  ushort_t* khB = (ushort_t*)(ws + O_KH);
  ushort_t* klB = (ushort_t*)(ws + O_KL);
  ushort_t* vth = (ushort_t*)(ws + O_VTH);
  ushort_t* vtl = (ushort_t*)(ws + O_VTL);
  float* cosT   = ws + O_COS;
  float* sinT   = ws + O_SIN;
  float* logits = ws + O_LOG;
  float* topw   = ws + O_TPW;
  ushort_t* wTh = (ushort_t*)(ws + O_WTH);
  ushort_t* wTl = (ushort_t*)(ws + O_WTL);
  float* sc     = dws;                          // 32 heads f32 scores (32MF)
  ushort_t* ph  = (ushort_t*)(dws + 32*MF);     // P hi (16MF)
  ushort_t* pl  = (ushort_t*)(ws + O_SC);       // P lo (16MF, ws dead region)
  ushort_t* wQh = (ushort_t*)dws;               // QKV weight hi (consumed pre-qk3)
  ushort_t* wQl = (ushort_t*)(dws + MF);
  ushort_t* xgh = (ushort_t*)(ws + O_XGH);
  ushort_t* xgl = (ushort_t*)(ws + O_XGL);
  ushort_t* wAh = (ushort_t*)dws;               // merged expert weight hi (16MF)
  ushort_t* wAl = (ushort_t*)(dws + 16*MF);     // merged expert weight lo (16MF)
  float* hb     = ws + O_HB;                    // combined h1|h3 f32 [MROW][4096]
  ushort_t* h13h= (ushort_t*)(ws + O_H13H);
  ushort_t* h13l= (ushort_t*)(ws + O_H13L);
  float* y      = ws + O_Y;
  ushort_t* owTh= (ushort_t*)(ws + O_SC);       // LM weight hi
  int* ip = (int*)(ws + O_INT);
  int* counts  = ip;
  int* counts2 = ip + 8;
  int* bases   = ip + 16;
  int* sel     = ip + 32;
  int* row2tok = ip + 32 + 4096;
  int* posof   = ip + 32 + 8192;

  k_rope_table<<<128, 256, 0, stream>>>(pos, cosT, sinT);
  k_embed<<<Nq, 256, 0, stream>>>(ids, tok_emb, h);

  for (int l = 0; l < Lq; l++) {
    // ---- attention ----
    k_rmsnorm3<<<Nq, 256, 0, stream>>>(h, attn_nw + (size_t)l * Dq, xh, xl);
    k_convT2<<<dim3(32, 32, 1), 256, 0, stream>>>(wq + (long long)l*Dq*Hq*HDq, wQh, wQl, Hq*HDq, Dq, 1, 0, 0, 0);
    k_convT2<<<dim3(8, 32, 1), 256, 0, stream>>>(wk + (long long)l*Dq*KVq*HDq, wQh + (size_t)1024*1024, wQl + (size_t)1024*1024, KVq*HDq, Dq, 1, 0, 0, 0);
    k_convT2<<<dim3(8, 32, 1), 256, 0, stream>>>(wv + (long long)l*Dq*KVq*HDq, wQh + (size_t)1280*1024, wQl + (size_t)1280*1024, KVq*HDq, Dq, 1, 0, 0, 0);
    k_mgemm3<<<dim3(16, 12, 1), 256, 0, stream>>>(xh, xl, wQh, wQl, qkv, 1536, Dq, Dq, 1536, 0, 0, nullptr, nullptr, Nq);
    k_rope3<<<(Nq * 20 * 32) / 256, 256, 0, stream>>>(qkv, cosT, sinT, qhB, qlB, khB, klB);
    k_convT2<<<dim3(2, 32, Bq*KVq), 256, 0, stream>>>(qkv + 1280, vth, vtl, 1536, Sq,
           KVq, (long long)Sq*1536, HDq, (long long)HDq*Sq);
    k_qk3<<<dim3(8, 8, 32), 256, 0, stream>>>(qhB, qlB, khB, klB, sc);
    k_softmax3<<<(32 * Sq) / 4, 256, 0, stream>>>(sc, ph, pl);
    k_pv3<<<dim3(8, 1, 32), 256, 0, stream>>>(ph, pl, vth, vtl, ath, atl);
    k_convT2<<<dim3(32, 32, 1), 256, 0, stream>>>(wo + (long long)l*Hq*HDq*Dq, wTh, wTl, Dq, Hq*HDq, 1, 0, 0, 0);
    k_mgemm3<<<dim3(16, 8, 1), 256, 0, stream>>>(ath, atl, wTh, wTl, h, Dq, Hq*HDq, Hq*HDq, Dq, 1, 0, nullptr, nullptr, Nq);

    // ---- MoE ----
    k_rmsnorm3<<<Nq, 256, 0, stream>>>(h, ffn_nw + (size_t)l * Dq, xh, xl);
    k_gate<<<Nq / 4, 256, 0, stream>>>(xh, xl, gate + (size_t)l * Dq * Eq, logits);
    k_zero_counts<<<1, 32, 0, stream>>>(counts);
    k_route_count<<<Nq / 256, 256, 0, stream>>>(logits, topw, sel, counts);
    k_scan<<<1, 1, 0, stream>>>(counts, bases, counts2);
    k_route_assign<<<Nq / 256, 256, 0, stream>>>(sel, counts2, bases, row2tok, posof);
    k_gather_us<<<MROW, 256, 0, stream>>>(xh, xl, row2tok, xgh, xgl);
    int last = (l == Lq - 1);   // no routing downstream of last MoE -> 1-pass bf16
    // merged [w1|w3]: expert weight rows 0-2047 = w1, 2048-4095 = w3
    k_convT2<<<dim3(64, 32, 8), 256, 0, stream>>>(w1 + (long long)l*Eq*Dq*Fq, wAh, last ? nullptr : wAl,
           Fq, Dq, 1, (long long)Dq*Fq, 0, (long long)4096*1024);
    k_convT2<<<dim3(64, 32, 8), 256, 0, stream>>>(w3 + (long long)l*Eq*Dq*Fq,
           wAh + (size_t)2048*1024, last ? nullptr : (wAl + (size_t)2048*1024),
           Fq, Dq, 1, (long long)Dq*Fq, 0, (long long)4096*1024);
    if (last) k_mgemm1<<<dim3(16, 32, 8), 256, 0, stream>>>(xgh, wAh, hb, 4096, Dq, Dq, 4096, 0, 1, bases, counts, 0);
    else      k_mgemm3<<<dim3(16, 32, 8), 256, 0, stream>>>(xgh, xgl, wAh, wAl, hb, 4096, Dq, Dq, 4096, 0, 1, bases, counts, 0);
    k_silumul3b<<<4096, 256, 0, stream>>>(hb, h13h, h13l);
    // w2
    k_convT2<<<dim3(32, 64, 8), 256, 0, stream>>>(w2 + (long long)l*Eq*Fq*Dq, wAh, last ? nullptr : wAl,
           Dq, Fq, 1, (long long)Fq*Dq, 0, (long long)Dq*Fq);
    if (last) k_mgemm1<<<dim3(16, 8, 8), 256, 0, stream>>>(h13h, wAh, y, Dq, Fq, Fq, Dq, 0, 1, bases, counts, 0);
    else      k_mgemm3<<<dim3(16, 8, 8), 256, 0, stream>>>(h13h, h13l, wAh, wAl, y, Dq, Fq, Fq, Dq, 0, 1, bases, counts, 0);
    k_moe_combine<<<Nq, 256, 0, stream>>>(h, y, topw, posof);
  }

  // ---- final norm + LM head (1-pass bf16, 128x128, gload_lds, XCD swizzle) ----
  k_rmsnorm3<<<Nq, 256, 0, stream>>>(h, fnw, xh, xl);
  k_convT2<<<dim3(1000, 32, 1), 256, 0, stream>>>(outw, owTh, nullptr, Vq, Dq, 1, 0, 0, 0);
  k_mgemm1<<<dim3(16, 250, 1), 256, 0, stream>>>(xh, owTh, out, Vq, Dq, Dq, Vq, 0, 0, nullptr, nullptr, Nq);
}

// Round 14
// 1450.714 us; speedup vs baseline: 1.5861x; 1.0168x over previous
//
#include <hip/hip_runtime.h>
#include <math.h>

typedef unsigned short ushort_t;
typedef __attribute__((ext_vector_type(8))) short short8;
typedef __attribute__((ext_vector_type(4))) float f32x4;

// ---------------- problem constants ----------------
#define Bq 2
#define Sq 1024
#define Dq 1024
#define Lq 2
#define HDq 64
#define Hq 16
#define KVq 4
#define Fq 2048
#define Eq 8
#define TOPK 2
#define Vq 32000
#define Nq (Bq*Sq)
#define EPSq 1e-5f
#define MROW (Nq*TOPK)

__device__ __forceinline__ float b2f(ushort_t u) {
  return __uint_as_float(((unsigned int)u) << 16);
}
__device__ __forceinline__ ushort_t f2b(float f) {
  unsigned int u = __float_as_uint(f);
  u += 0x7fffu + ((u >> 16) & 1u);   // RNE
  return (ushort_t)(u >> 16);
}

// async global->LDS (16B per lane)
typedef const void __attribute__((address_space(1)))* gas_cptr;
typedef void __attribute__((address_space(3)))* las_ptr;
__device__ __forceinline__ void gload16(const void* g, void* l) {
  __builtin_amdgcn_global_load_lds((gas_cptr)g, (las_ptr)l, 16, 0, 0);
}

// bijective XCD-aware swizzle of the (x,y) block plane (m204 formula)
__device__ __forceinline__ void xcd_tiles(int &bx, int &by) {
  int gx = gridDim.x;
  int nwg = gx * gridDim.y;
  int bid = blockIdx.y * gx + blockIdx.x;
  int q8 = nwg >> 3, r8 = nwg & 7;
  int xcd = bid & 7, idx = bid >> 3;
  int swz = (xcd < r8) ? xcd * (q8 + 1) + idx
                       : r8 * (q8 + 1) + (xcd - r8) * q8 + idx;
  bx = swz % gx;
  by = swz / gx;
}

// ---------------- workspace layout (float offsets) ----------------
#define MF ((size_t)1024*1024)
#define O_H    ((size_t)0)
#define O_XH   (2*MF)
#define O_XL   (3*MF)
#define O_QKV  (4*MF)
#define O_ATH  (7*MF)
#define O_ATL  (8*MF)
#define O_QH   (9*MF)
#define O_QL   (10*MF)
#define O_KH   (11*MF)
#define O_KL   (11*MF + MF/4)
#define O_VTH  (11*MF + MF/2)
#define O_VTL  (11*MF + 3*MF/4)
#define O_COS  (12*MF)
#define O_SIN  (O_COS + 32768)
#define O_LOG  (O_SIN + 32768)
#define O_TPW  (O_LOG + 16384)
#define O_WTH  (O_COS + MF/8)
#define O_WTL  (O_WTH + MF/2)
#define O_SC   (27*MF/2)              // P lo (attn) / MoE hb / LM weight
// MoE overlays:
#define O_XGH  (4*MF)
#define O_XGL  (6*MF)
#define O_HB   (O_SC)                 // combined [MROW][4096] f32 (16MF)
#define O_H13H (O_SC + 16*MF)
#define O_H13L (O_SC + 20*MF)
#define O_Y    (O_SC + 24*MF)
#define O_INT  (42*MF)

// ---------------- small kernels ----------------

__global__ void k_rope_table(const int* __restrict__ pos, float* __restrict__ cosT,
                             float* __restrict__ sinT) {
  int i = blockIdx.x * blockDim.x + threadIdx.x;
  if (i >= Sq * 32) return;
  int s = i >> 5, f = i & 31;
  float freq = 1.0f / powf(1.0e6f, (float)f / 32.0f);
  float ang = (float)pos[s] * freq;
  cosT[i] = cosf(ang);
  sinT[i] = sinf(ang);
}

__global__ void k_embed(const int* __restrict__ ids, const float* __restrict__ emb,
                        float* __restrict__ h) {
  int n = blockIdx.x;
  const float4* src = (const float4*)(emb + (size_t)ids[n] * Dq);
  float4* dst = (float4*)(h + (size_t)n * Dq);
  dst[threadIdx.x] = src[threadIdx.x];
}

__global__ void k_rmsnorm3(const float* __restrict__ in, const float* __restrict__ w,
                           ushort_t* __restrict__ outh, ushort_t* __restrict__ outl) {
  int n = blockIdx.x;
  int t = threadIdx.x;
  float4 v = ((const float4*)(in + (size_t)n * Dq))[t];
  float ss = v.x*v.x + v.y*v.y + v.z*v.z + v.w*v.w;
  #pragma unroll
  for (int o = 32; o > 0; o >>= 1) ss += __shfl_down(ss, o);
  __shared__ float red[4];
  if ((t & 63) == 0) red[t >> 6] = ss;
  __syncthreads();
  float tot = red[0] + red[1] + red[2] + red[3];
  float r = rsqrtf(tot / (float)Dq + EPSq);
  float4 wl = ((const float4*)w)[t];
  float o4[4];
  o4[0] = v.x * r * wl.x; o4[1] = v.y * r * wl.y;
  o4[2] = v.z * r * wl.z; o4[3] = v.w * r * wl.w;
  ushort_t* oh = outh + (size_t)n * Dq + t * 4;
  ushort_t* ol = outl + (size_t)n * Dq + t * 4;
  #pragma unroll
  for (int j = 0; j < 4; j++) {
    ushort_t hi = f2b(o4[j]);
    oh[j] = hi;
    ol[j] = f2b(o4[j] - b2f(hi));
  }
}

// fused rope + hi/lo split from combined qkv buffer (row stride 1536)
__global__ void k_rope3(const float* __restrict__ qkv, const float* __restrict__ cosT,
                        const float* __restrict__ sinT,
                        ushort_t* __restrict__ qh, ushort_t* __restrict__ ql,
                        ushort_t* __restrict__ kh, ushort_t* __restrict__ kl) {
  int i = blockIdx.x * blockDim.x + threadIdx.x;
  int n = i / 640, r = i % 640;
  int hh = r >> 5, f = r & 31;
  int s = n & (Sq - 1);
  float c = cosT[s * 32 + f], sn = sinT[s * 32 + f];
  int srcCol = (hh < 16) ? hh * 64 + 2 * f : 1024 + (hh - 16) * 64 + 2 * f;
  const float* pp = qkv + (size_t)n * 1536 + srcCol;
  float xe = pp[0], xo = pp[1];
  float re = xe * c - xo * sn;
  float im = xe * sn + xo * c;
  ushort_t reh = f2b(re), imh = f2b(im);
  ushort_t rel = f2b(re - b2f(reh)), iml = f2b(im - b2f(imh));
  if (hh < 16) {
    size_t d = (size_t)n * 1024 + hh * 64 + 2 * f;
    qh[d] = reh; qh[d + 1] = imh;
    ql[d] = rel; ql[d + 1] = iml;
  } else {
    size_t d = (size_t)n * 256 + (hh - 16) * 64 + 2 * f;
    kh[d] = reh; kh[d + 1] = imh;
    kl[d] = rel; kl[d + 1] = iml;
  }
}

// tiled transpose + f32->bf16 hi/lo split; dl==nullptr -> hi only
__global__ void k_convT2(const float* __restrict__ src, ushort_t* __restrict__ dh,
                         ushort_t* __restrict__ dl, int srcStride, int dstStride,
                         int zdiv, long long srcZa, long long srcZb, long long dstZ) {
  __shared__ float tile[32][33];
  int z = blockIdx.z;
  const float* s = src + (long long)(z / zdiv) * srcZa + (long long)(z % zdiv) * srcZb;
  int r0 = blockIdx.y * 32, c0 = blockIdx.x * 32;
  int tc = threadIdx.x & 31, tr = threadIdx.x >> 5;
  #pragma unroll
  for (int i = 0; i < 4; ++i)
    tile[tr + i * 8][tc] = s[(long long)(r0 + tr + i * 8) * srcStride + c0 + tc];
  __syncthreads();
  #pragma unroll
  for (int i = 0; i < 4; ++i) {
    float v = tile[tc][tr + i * 8];
    ushort_t hi = f2b(v);
    long long idx = (long long)z * dstZ + (long long)(c0 + tr + i * 8) * dstStride + r0 + tc;
    dh[idx] = hi;
    if (dl) dl[idx] = f2b(v - b2f(hi));
  }
}

// ---------------- fused bf16x3 MFMA GEMM (gload_lds + swizzle + XCD) ----------
__global__ __launch_bounds__(256)
void k_mgemm3(const ushort_t* __restrict__ Ah, const ushort_t* __restrict__ Al,
              const ushort_t* __restrict__ Bh, const ushort_t* __restrict__ Bl,
              float* __restrict__ C,
              int N, int Kd, int lda, int ldc,
              int outmode, int mode,
              const int* __restrict__ grpBase, const int* __restrict__ grpCnt, int M) {
  __shared__ alignas(16) short Ash[128 * 64];
  __shared__ alignas(16) short Asl[128 * 64];
  __shared__ alignas(16) short Bsh[128 * 64];
  __shared__ alignas(16) short Bsl[128 * 64];
  int z = blockIdx.z;
  const ushort_t *Abh, *Abl, *Bbh, *Bbl;
  long long cOff;
  int Me = M;
  if (mode == 1) {
    int base = grpBase[z];
    Me = grpCnt[z];
    Abh = Ah + (long long)base * lda;
    Abl = Al + (long long)base * lda;
    long long bo = (long long)z * ((long long)N * Kd);
    Bbh = Bh + bo; Bbl = Bl + bo;
    cOff = (long long)base * ldc;
  } else {
    Abh = Ah; Abl = Al; Bbh = Bh; Bbl = Bl; cOff = 0;
  }
  int bx, by;
  xcd_tiles(bx, by);
  int m0 = bx * 128, n0 = by * 128;
  if (m0 >= Me) return;
  int t = threadIdx.x, w = t >> 6, lane = t & 63;
  int wm = w >> 1, wn = w & 1;
  int rA = lane >> 3;
  int sOff = ((lane & 7) ^ rA) << 3;
  f32x4 acc[4][4];
  #pragma unroll
  for (int i = 0; i < 4; ++i)
    #pragma unroll
    for (int j = 0; j < 4; ++j) { acc[i][j].x = 0.f; acc[i][j].y = 0.f; acc[i][j].z = 0.f; acc[i][j].w = 0.f; }
  int nkt = Kd >> 6;
  for (int kt = 0; kt < nkt; ++kt) {
    int k0 = kt << 6;
    #pragma unroll
    for (int i = 0; i < 4; ++i) {
      int j = (w << 2) + i;
      int row = (j << 3) + rA;
      long long ao = (long long)(m0 + row) * lda + k0 + sOff;
      long long bo = (long long)(n0 + row) * Kd + k0 + sOff;
      gload16(Abh + ao, &Ash[j * 512]);
      gload16(Abl + ao, &Asl[j * 512]);
      gload16(Bbh + bo, &Bsh[j * 512]);
      gload16(Bbl + bo, &Bsl[j * 512]);
    }
    __syncthreads();
    #pragma unroll
    for (int kk = 0; kk < 2; ++kk) {
      short8 afh[4], afl[4], bfh[4], bfl[4];
      int cl = (kk << 2) + (lane >> 4);
      #pragma unroll
      for (int mi = 0; mi < 4; ++mi) {
        int row = (wm << 6) + (mi << 4) + (lane & 15);
        int idx = (row << 6) + ((cl ^ (row & 7)) << 3);
        afh[mi] = *(const short8*)&Ash[idx];
        afl[mi] = *(const short8*)&Asl[idx];
      }
      #pragma unroll
      for (int nj = 0; nj < 4; ++nj) {
        int row = (wn << 6) + (nj << 4) + (lane & 15);
        int idx = (row << 6) + ((cl ^ (row & 7)) << 3);
        bfh[nj] = *(const short8*)&Bsh[idx];
        bfl[nj] = *(const short8*)&Bsl[idx];
      }
      #pragma unroll
      for (int mi = 0; mi < 4; ++mi)
        #pragma unroll
        for (int nj = 0; nj < 4; ++nj) {
          acc[mi][nj] = __builtin_amdgcn_mfma_f32_16x16x32_bf16(afh[mi], bfh[nj], acc[mi][nj], 0, 0, 0);
          acc[mi][nj] = __builtin_amdgcn_mfma_f32_16x16x32_bf16(afl[mi], bfh[nj], acc[mi][nj], 0, 0, 0);
          acc[mi][nj] = __builtin_amdgcn_mfma_f32_16x16x32_bf16(afh[mi], bfl[nj], acc[mi][nj], 0, 0, 0);
        }
    }
    __syncthreads();
  }
  #pragma unroll
  for (int mi = 0; mi < 4; ++mi) {
    #pragma unroll
    for (int nj = 0; nj < 4; ++nj) {
      int col = n0 + (wn << 6) + (nj << 4) + (lane & 15);
      if (col >= N) continue;
      #pragma unroll
      for (int r = 0; r < 4; ++r) {
        int lr = m0 + (wm << 6) + (mi << 4) + (lane >> 4) * 4 + r;
        if (lr >= Me) continue;
        long long ci = cOff + (long long)lr * ldc + col;
        float v = ((float*)&acc[mi][nj])[r];
        if (outmode == 0) C[ci] = v;
        else C[ci] += v;
      }
    }
  }
}

// ---------------- 1-pass bf16 MFMA GEMM, 2-phase pipelined ----------
__global__ __launch_bounds__(256)
void k_mgemm1(const ushort_t* __restrict__ Ah, const ushort_t* __restrict__ Bh,
              float* __restrict__ C,
              int N, int Kd, int lda, int ldc,
              int outmode, int mode,
              const int* __restrict__ grpBase, const int* __restrict__ grpCnt, int M) {
  __shared__ alignas(16) short Ash[2][128 * 64];
  __shared__ alignas(16) short Bsh[2][128 * 64];
  int z = blockIdx.z;
  const ushort_t *Abh, *Bbh;
  long long cOff;
  int Me = M;
  if (mode == 1) {
    int base = grpBase[z];
    Me = grpCnt[z];
    Abh = Ah + (long long)base * lda;
    Bbh = Bh + (long long)z * ((long long)N * Kd);
    cOff = (long long)base * ldc;
  } else {
    Abh = Ah; Bbh = Bh; cOff = 0;
  }
  int bx, by;
  xcd_tiles(bx, by);
  int m0 = bx * 128, n0 = by * 128;
  if (m0 >= Me) return;
  int t = threadIdx.x, w = t >> 6, lane = t & 63;
  int wm = w >> 1, wn = w & 1;
  int rA = lane >> 3;
  int sOff = ((lane & 7) ^ rA) << 3;
  f32x4 acc[4][4];
  #pragma unroll
  for (int i = 0; i < 4; ++i)
    #pragma unroll
    for (int j = 0; j < 4; ++j) { acc[i][j].x = 0.f; acc[i][j].y = 0.f; acc[i][j].z = 0.f; acc[i][j].w = 0.f; }
  int nkt = Kd >> 6;
  // prologue: stage kt=0 into buf 0
  #pragma unroll
  for (int i = 0; i < 4; ++i) {
    int j = (w << 2) + i;
    int row = (j << 3) + rA;
    gload16(Abh + (long long)(m0 + row) * lda + sOff, &Ash[0][j * 512]);
    gload16(Bbh + (long long)(n0 + row) * Kd + sOff, &Bsh[0][j * 512]);
  }
  __syncthreads();
  int cur = 0;
  for (int kt = 0; kt < nkt; ++kt) {
    // issue next tile's loads (overlap with compute below)
    if (kt + 1 < nkt) {
      int k0 = (kt + 1) << 6;
      #pragma unroll
      for (int i = 0; i < 4; ++i) {
        int j = (w << 2) + i;
        int row = (j << 3) + rA;
        gload16(Abh + (long long)(m0 + row) * lda + k0 + sOff, &Ash[cur ^ 1][j * 512]);
        gload16(Bbh + (long long)(n0 + row) * Kd + k0 + sOff, &Bsh[cur ^ 1][j * 512]);
      }
    }
    // compute current buffer
    #pragma unroll
    for (int kk = 0; kk < 2; ++kk) {
      short8 afh[4], bfh[4];
      int cl = (kk << 2) + (lane >> 4);
      #pragma unroll
      for (int mi = 0; mi < 4; ++mi) {
        int row = (wm << 6) + (mi << 4) + (lane & 15);
        afh[mi] = *(const short8*)&Ash[cur][(row << 6) + ((cl ^ (row & 7)) << 3)];
      }
      #pragma unroll
      for (int nj = 0; nj < 4; ++nj) {
        int row = (wn << 6) + (nj << 4) + (lane & 15);
        bfh[nj] = *(const short8*)&Bsh[cur][(row << 6) + ((cl ^ (row & 7)) << 3)];
      }
      #pragma unroll
      for (int mi = 0; mi < 4; ++mi)
        #pragma unroll
        for (int nj = 0; nj < 4; ++nj)
          acc[mi][nj] = __builtin_amdgcn_mfma_f32_16x16x32_bf16(afh[mi], bfh[nj], acc[mi][nj], 0, 0, 0);
    }
    __syncthreads();   // drains in-flight loads (vmcnt 0) + compute done
    cur ^= 1;
  }
  #pragma unroll
  for (int mi = 0; mi < 4; ++mi) {
    #pragma unroll
    for (int nj = 0; nj < 4; ++nj) {
      int col = n0 + (wn << 6) + (nj << 4) + (lane & 15);
      if (col >= N) continue;
      #pragma unroll
      for (int r = 0; r < 4; ++r) {
        int lr = m0 + (wm << 6) + (mi << 4) + (lane >> 4) * 4 + r;
        if (lr >= Me) continue;
        long long ci = cOff + (long long)lr * ldc + col;
        float v = ((float*)&acc[mi][nj])[r];
        if (outmode == 0) C[ci] = v;
        else C[ci] += v;
      }
    }
  }
}

// ---------------- attention QK^T (gload_lds + swizzle, causal skip) ----------
__global__ __launch_bounds__(256)
void k_qk3(const ushort_t* __restrict__ qh, const ushort_t* __restrict__ ql,
           const ushort_t* __restrict__ kh, const ushort_t* __restrict__ kl,
           float* __restrict__ sc) {
  __shared__ alignas(16) short Ash[128 * 64];
  __shared__ alignas(16) short Asl[128 * 64];
  __shared__ alignas(16) short Bsh[128 * 64];
  __shared__ alignas(16) short Bsl[128 * 64];
  int zl = blockIdx.z;
  int b = zl >> 4, hh = zl & 15, kv = hh >> 2;
  int m0 = blockIdx.x * 128, n0 = blockIdx.y * 128;
  if (n0 > m0 + 127) return;
  long long aBase = ((long long)(b * Sq) * Hq + hh) * HDq;
  long long bBase = ((long long)(b * Sq) * KVq + kv) * HDq;
  int t = threadIdx.x, w = t >> 6, lane = t & 63;
  int wm = w >> 1, wn = w & 1;
  int rA = lane >> 3;
  int sOff = ((lane & 7) ^ rA) << 3;
  f32x4 acc[4][4];
  #pragma unroll
  for (int i = 0; i < 4; ++i)
    #pragma unroll
    for (int j = 0; j < 4; ++j) { acc[i][j].x = 0.f; acc[i][j].y = 0.f; acc[i][j].z = 0.f; acc[i][j].w = 0.f; }
  {
    #pragma unroll
    for (int i = 0; i < 4; ++i) {
      int j = (w << 2) + i;
      int row = (j << 3) + rA;
      long long ao = aBase + (long long)(m0 + row) * (Hq * HDq) + sOff;
      long long bo = bBase + (long long)(n0 + row) * (KVq * HDq) + sOff;
      gload16(qh + ao, &Ash[j * 512]);
      gload16(ql + ao, &Asl[j * 512]);
      gload16(kh + bo, &Bsh[j * 512]);
      gload16(kl + bo, &Bsl[j * 512]);
    }
    __syncthreads();
    #pragma unroll
    for (int kk = 0; kk < 2; ++kk) {
      short8 afh[4], afl[4], bfh[4], bfl[4];
      int cl = (kk << 2) + (lane >> 4);
      #pragma unroll
      for (int mi = 0; mi < 4; ++mi) {
        int row = (wm << 6) + (mi << 4) + (lane & 15);
        int idx = (row << 6) + ((cl ^ (row & 7)) << 3);
        afh[mi] = *(const short8*)&Ash[idx];
        afl[mi] = *(const short8*)&Asl[idx];
      }
      #pragma unroll
      for (int nj = 0; nj < 4; ++nj) {
        int row = (wn << 6) + (nj << 4) + (lane & 15);
        int idx = (row << 6) + ((cl ^ (row & 7)) << 3);
        bfh[nj] = *(const short8*)&Bsh[idx];
        bfl[nj] = *(const short8*)&Bsl[idx];
      }
      #pragma unroll
      for (int mi = 0; mi < 4; ++mi)
        #pragma unroll
        for (int nj = 0; nj < 4; ++nj) {
          acc[mi][nj] = __builtin_amdgcn_mfma_f32_16x16x32_bf16(afh[mi], bfh[nj], acc[mi][nj], 0, 0, 0);
          acc[mi][nj] = __builtin_amdgcn_mfma_f32_16x16x32_bf16(afl[mi], bfh[nj], acc[mi][nj], 0, 0, 0);
          acc[mi][nj] = __builtin_amdgcn_mfma_f32_16x16x32_bf16(afh[mi], bfl[nj], acc[mi][nj], 0, 0, 0);
        }
    }
  }
  float* out = sc + (long long)zl * Sq * Sq;
  #pragma unroll
  for (int mi = 0; mi < 4; ++mi) {
    #pragma unroll
    for (int nj = 0; nj < 4; ++nj) {
      int col = n0 + (wn << 6) + (nj << 4) + (lane & 15);
      #pragma unroll
      for (int r = 0; r < 4; ++r) {
        int lr = m0 + (wm << 6) + (mi << 4) + (lane >> 4) * 4 + r;
        out[(long long)lr * Sq + col] = ((float*)&acc[mi][nj])[r] * 0.125f;
      }
    }
  }
}

// causal softmax; reads f32 sc (32 heads), writes P hi/lo bf16
__global__ __launch_bounds__(256)
void k_softmax3(const float* __restrict__ sc, ushort_t* __restrict__ ph,
                ushort_t* __restrict__ pl) {
  int row = blockIdx.x * 4 + (threadIdx.x >> 6);
  int lane = threadIdx.x & 63;
  int qi = row & (Sq - 1);
  const float* p = sc + (long long)row * Sq;
  float vals[16];
  float mx = -3.0e38f;
  #pragma unroll
  for (int j = 0; j < 16; j++) {
    int idx = lane + j * 64;
    float v = (idx <= qi) ? p[idx] : -3.0e38f;
    vals[j] = v;
    mx = fmaxf(mx, v);
  }
  #pragma unroll
  for (int o = 32; o > 0; o >>= 1) mx = fmaxf(mx, __shfl_xor(mx, o));
  float sum = 0.0f;
  #pragma unroll
  for (int j = 0; j < 16; j++) {
    int idx = lane + j * 64;
    float e = (idx <= qi) ? expf(vals[j] - mx) : 0.0f;
    vals[j] = e;
    sum += e;
  }
  #pragma unroll
  for (int o = 32; o > 0; o >>= 1) sum += __shfl_xor(sum, o);
  float inv = 1.0f / sum;
  long long base = (long long)row * Sq;
  #pragma unroll
  for (int j = 0; j < 16; j++) {
    int idx = lane + j * 64;
    float pr = vals[j] * inv;
    ushort_t hi = f2b(pr);
    ph[base + idx] = hi;
    pl[base + idx] = f2b(pr - b2f(hi));
  }
}

// attention PV (gload_lds + swizzle, triangular K bound). grid (8, 1, 32).
__global__ __launch_bounds__(256)
void k_pv3(const ushort_t* __restrict__ ph, const ushort_t* __restrict__ pl,
           const ushort_t* __restrict__ vth, const ushort_t* __restrict__ vtl,
           ushort_t* __restrict__ ath, ushort_t* __restrict__ atl) {
  __shared__ alignas(16) short Ash[128 * 64];
  __shared__ alignas(16) short Asl[128 * 64];
  __shared__ alignas(16) short Bsh[128 * 64];
  __shared__ alignas(16) short Bsl[128 * 64];
  int zl = blockIdx.z;
  int b = zl >> 4, hh = zl & 15, kv = hh >> 2;
  int m0 = blockIdx.x * 128;
  const ushort_t* Abh = ph + (long long)zl * Sq * Sq;
  const ushort_t* Abl = pl + (long long)zl * Sq * Sq;
  const ushort_t* Bbh = vth + (long long)((b * KVq + kv) * HDq) * Sq;
  const ushort_t* Bbl = vtl + (long long)((b * KVq + kv) * HDq) * Sq;
  int t = threadIdx.x, w = t >> 6, lane = t & 63;
  int wm = w >> 1, wn = w & 1;
  int rA = lane >> 3;
  int sOff = ((lane & 7) ^ rA) << 3;
  f32x4 acc[4][4];
  #pragma unroll
  for (int i = 0; i < 4; ++i)
    #pragma unroll
    for (int j = 0; j < 4; ++j) { acc[i][j].x = 0.f; acc[i][j].y = 0.f; acc[i][j].z = 0.f; acc[i][j].w = 0.f; }
  int ktmax = 2 * blockIdx.x + 2;
  for (int kt = 0; kt < ktmax; ++kt) {
    int k0 = kt << 6;
    #pragma unroll
    for (int i = 0; i < 4; ++i) {
      int j = (w << 2) + i;
      int row = (j << 3) + rA;
      long long ao = (long long)(m0 + row) * Sq + k0 + sOff;
      long long bo = (long long)(row & 63) * Sq + k0 + sOff;
      gload16(Abh + ao, &Ash[j * 512]);
      gload16(Abl + ao, &Asl[j * 512]);
      gload16(Bbh + bo, &Bsh[j * 512]);
      gload16(Bbl + bo, &Bsl[j * 512]);
    }
    __syncthreads();
    #pragma unroll
    for (int kk = 0; kk < 2; ++kk) {
      short8 afh[4], afl[4], bfh[4], bfl[4];
      int cl = (kk << 2) + (lane >> 4);
      #pragma unroll
      for (int mi = 0; mi < 4; ++mi) {
        int row = (wm << 6) + (mi << 4) + (lane & 15);
        int idx = (row << 6) + ((cl ^ (row & 7)) << 3);
        afh[mi] = *(const short8*)&Ash[idx];
        afl[mi] = *(const short8*)&Asl[idx];
      }
      #pragma unroll
      for (int nj = 0; nj < 4; ++nj) {
        int row = (wn << 6) + (nj << 4) + (lane & 15);
        int idx = (row << 6) + ((cl ^ (row & 7)) << 3);
        bfh[nj] = *(const short8*)&Bsh[idx];
        bfl[nj] = *(const short8*)&Bsl[idx];
      }
      #pragma unroll
      for (int mi = 0; mi < 4; ++mi)
        #pragma unroll
        for (int nj = 0; nj < 4; ++nj) {
          acc[mi][nj] = __builtin_amdgcn_mfma_f32_16x16x32_bf16(afh[mi], bfh[nj], acc[mi][nj], 0, 0, 0);
          acc[mi][nj] = __builtin_amdgcn_mfma_f32_16x16x32_bf16(afl[mi], bfh[nj], acc[mi][nj], 0, 0, 0);
          acc[mi][nj] = __builtin_amdgcn_mfma_f32_16x16x32_bf16(afh[mi], bfl[nj], acc[mi][nj], 0, 0, 0);
        }
    }
    __syncthreads();
  }
  #pragma unroll
  for (int mi = 0; mi < 4; ++mi) {
    #pragma unroll
    for (int nj = 0; nj < 4; ++nj) {
      int col = (wn << 6) + (nj << 4) + (lane & 15);
      if (col >= HDq) continue;
      #pragma unroll
      for (int r = 0; r < 4; ++r) {
        int lr = m0 + (wm << 6) + (mi << 4) + (lane >> 4) * 4 + r;
        long long ci = ((long long)(b * Sq + lr)) * (Hq * HDq) + hh * HDq + col;
        float v = ((float*)&acc[mi][nj])[r];
        ushort_t hi = f2b(v);
        ath[ci] = hi;
        atl[ci] = f2b(v - b2f(hi));
      }
    }
  }
}

// ---------------- MoE routing ----------------
__global__ void k_gate(const ushort_t* __restrict__ xh, const ushort_t* __restrict__ xl,
                       const float* __restrict__ gw, float* __restrict__ logits) {
  int n = blockIdx.x * 4 + (threadIdx.x >> 6);
  int lane = threadIdx.x & 63;
  float acc[Eq];
  #pragma unroll
  for (int e = 0; e < Eq; e++) acc[e] = 0.0f;
  for (int d = lane; d < Dq; d += 64) {
    size_t idx = (size_t)n * Dq + d;
    float xv = b2f(xh[idx]) + b2f(xl[idx]);
    const float* g = gw + (size_t)d * Eq;
    #pragma unroll
    for (int e = 0; e < Eq; e++) acc[e] += xv * g[e];
  }
  #pragma unroll
  for (int o = 32; o > 0; o >>= 1)
    #pragma unroll
    for (int e = 0; e < Eq; e++) acc[e] += __shfl_xor(acc[e], o);
  if (lane == 0) {
    #pragma unroll
    for (int e = 0; e < Eq; e++) logits[(size_t)n * Eq + e] = acc[e];
  }
}

__global__ void k_zero_counts(int* c) { if (threadIdx.x < 16) c[threadIdx.x] = 0; }

__global__ void k_route_count(const float* __restrict__ logits, float* __restrict__ topw,
                              int* __restrict__ sel, int* __restrict__ counts) {
  int n = blockIdx.x * blockDim.x + threadIdx.x;
  if (n >= Nq) return;
  const float* lg = logits + (size_t)n * Eq;
  int i1 = 0; float v1 = lg[0];
  #pragma unroll
  for (int e = 1; e < Eq; e++) if (lg[e] > v1) { v1 = lg[e]; i1 = e; }
  int i2 = -1; float v2 = -3.0e38f;
  #pragma unroll
  for (int e = 0; e < Eq; e++) if (e != i1 && lg[e] > v2) { v2 = lg[e]; i2 = e; }
  float e2 = expf(v2 - v1);
  float s = 1.0f + e2;
  topw[n * 2 + 0] = 1.0f / s;
  topw[n * 2 + 1] = e2 / s;
  sel[n * 2 + 0] = i1;
  sel[n * 2 + 1] = i2;
  atomicAdd(&counts[i1], 1);
  atomicAdd(&counts[i2], 1);
}

__global__ void k_scan(const int* __restrict__ counts, int* __restrict__ bases,
                       int* __restrict__ counts2) {
  if (threadIdx.x == 0) {
    int s = 0;
    for (int e = 0; e < Eq; e++) { bases[e] = s; s += counts[e]; counts2[e] = 0; }
  }
}

__global__ void k_route_assign(const int* __restrict__ sel, int* __restrict__ counts2,
                               const int* __restrict__ bases, int* __restrict__ row2tok,
                               int* __restrict__ posof) {
  int n = blockIdx.x * blockDim.x + threadIdx.x;
  if (n >= Nq) return;
  #pragma unroll
  for (int slot = 0; slot < TOPK; slot++) {
    int e = sel[n * 2 + slot];
    int pos = atomicAdd(&counts2[e], 1);
    int row = bases[e] + pos;
    row2tok[row] = n;
    posof[n * 2 + slot] = row;
  }
}

__global__ void k_gather_us(const ushort_t* __restrict__ xh, const ushort_t* __restrict__ xl,
                            const int* __restrict__ row2tok,
                            ushort_t* __restrict__ xgh, ushort_t* __restrict__ xgl) {
  int row = blockIdx.x;
  int tok = row2tok[row];
  int t = threadIdx.x;
  const uint2* sh = (const uint2*)(xh + (size_t)tok * Dq);
  const uint2* sl = (const uint2*)(xl + (size_t)tok * Dq);
  ((uint2*)(xgh + (size_t)row * Dq))[t] = sh[t];
  ((uint2*)(xgl + (size_t)row * Dq))[t] = sl[t];
}

// silu(hb[:, :2048]) * hb[:, 2048:] -> hi/lo bf16
__global__ void k_silumul3b(const float* __restrict__ hb,
                            ushort_t* __restrict__ oh, ushort_t* __restrict__ ol) {
  long total = (long)MROW * Fq;
  long i = (long)blockIdx.x * blockDim.x + threadIdx.x;
  long st = (long)gridDim.x * blockDim.x;
  for (; i < total; i += st) {
    long r = i >> 11, f = i & 2047;
    float a = hb[(r << 12) + f];
    float b = hb[(r << 12) + 2048 + f];
    float s = (a / (1.0f + expf(-a))) * b;
    ushort_t hi = f2b(s);
    oh[i] = hi;
    ol[i] = f2b(s - b2f(hi));
  }
}

__global__ void k_moe_combine(float* __restrict__ h, const float* __restrict__ y,
                              const float* __restrict__ topw, const int* __restrict__ posof) {
  int n = blockIdx.x;
  int t = threadIdx.x;
  float w0 = topw[n * 2 + 0], w1 = topw[n * 2 + 1];
  int r0 = posof[n * 2 + 0], r1 = posof[n * 2 + 1];
  float4 a = ((const float4*)(y + (size_t)r0 * Dq))[t];
  float4 b = ((const float4*)(y + (size_t)r1 * Dq))[t];
  float4 hv = ((float4*)(h + (size_t)n * Dq))[t];
  hv.x += w0 * a.x + w1 * b.x;
  hv.y += w0 * a.y + w1 * b.y;
  hv.z += w0 * a.z + w1 * b.z;
  hv.w += w0 * a.w + w1 * b.w;
  ((float4*)(h + (size_t)n * Dq))[t] = hv;
}

// ---------------- launch ----------------
extern "C" void kernel_launch(void* const* d_in, const int* in_sizes, int n_in,
                              void* d_out, int out_size, void* d_ws, size_t ws_size,
                              hipStream_t stream) {
  const int* ids       = (const int*)d_in[0];
  const int* pos       = (const int*)d_in[1];
  const float* tok_emb = (const float*)d_in[2];
  const float* attn_nw = (const float*)d_in[3];
  const float* ffn_nw  = (const float*)d_in[4];
  const float* wq      = (const float*)d_in[5];
  const float* wk      = (const float*)d_in[6];
  const float* wv      = (const float*)d_in[7];
  const float* wo      = (const float*)d_in[8];
  const float* gate    = (const float*)d_in[9];
  const float* w1      = (const float*)d_in[10];
  const float* w2      = (const float*)d_in[11];
  const float* w3      = (const float*)d_in[12];
  const float* fnw     = (const float*)d_in[13];
  const float* outw    = (const float*)d_in[14];
  float* out = (float*)d_out;
  float* ws = (float*)d_ws;
  float* dws = out;   // phase scratch inside d_out (62.5 MF; fully rewritten by LM head)

  float* h      = ws + O_H;
  ushort_t* xh  = (ushort_t*)(ws + O_XH);
  ushort_t* xl  = (ushort_t*)(ws + O_XL);
  float* qkv    = ws + O_QKV;
  ushort_t* ath = (ushort_t*)(ws + O_ATH);
  ushort_t* atl = (ushort_t*)(ws + O_ATL);
  ushort_t* qhB = (ushort_t*)(ws + O_QH);
  ushort_t* qlB = (ushort_t*)(ws + O_QL);
  ushort_t* khB = (ushort_t*)(ws + O_KH);
  ushort_t* klB = (ushort_t*)(ws + O_KL);
  ushort_t* vth = (ushort_t*)(ws + O_VTH);
  ushort_t* vtl = (ushort_t*)(ws + O_VTL);
  float* cosT   = ws + O_COS;
  float* sinT   = ws + O_SIN;
  float* logits = ws + O_LOG;
  float* topw   = ws + O_TPW;
  ushort_t* wTh = (ushort_t*)(ws + O_WTH);
  ushort_t* wTl = (ushort_t*)(ws + O_WTL);
  float* sc     = dws;                          // 32 heads f32 scores (32MF)
  ushort_t* ph  = (ushort_t*)(dws + 32*MF);     // P hi (16MF)
  ushort_t* pl  = (ushort_t*)(ws + O_SC);       // P lo (16MF, ws dead region)
  ushort_t* wQh = (ushort_t*)dws;               // QKV weight hi (consumed pre-qk3)
  ushort_t* wQl = (ushort_t*)(dws + MF);
  ushort_t* xgh = (ushort_t*)(ws + O_XGH);
  ushort_t* xgl = (ushort_t*)(ws + O_XGL);
  ushort_t* wAh = (ushort_t*)dws;               // merged expert weight hi (16MF)
  ushort_t* wAl = (ushort_t*)(dws + 16*MF);     // merged expert weight lo (16MF)
  float* hb     = ws + O_HB;                    // combined h1|h3 f32 [MROW][4096]
  ushort_t* h13h= (ushort_t*)(ws + O_H13H);
  ushort_t* h13l= (ushort_t*)(ws + O_H13L);
  float* y      = ws + O_Y;
  ushort_t* owTh= (ushort_t*)(ws + O_SC);       // LM weight hi
  int* ip = (int*)(ws + O_INT);
  int* counts  = ip;
  int* counts2 = ip + 8;
  int* bases   = ip + 16;
  int* sel     = ip + 32;
  int* row2tok = ip + 32 + 4096;
  int* posof   = ip + 32 + 8192;

  k_rope_table<<<128, 256, 0, stream>>>(pos, cosT, sinT);
  k_embed<<<Nq, 256, 0, stream>>>(ids, tok_emb, h);

  for (int l = 0; l < Lq; l++) {
    // ---- attention ----
    k_rmsnorm3<<<Nq, 256, 0, stream>>>(h, attn_nw + (size_t)l * Dq, xh, xl);
    k_convT2<<<dim3(32, 32, 1), 256, 0, stream>>>(wq + (long long)l*Dq*Hq*HDq, wQh, wQl, Hq*HDq, Dq, 1, 0, 0, 0);
    k_convT2<<<dim3(8, 32, 1), 256, 0, stream>>>(wk + (long long)l*Dq*KVq*HDq, wQh + (size_t)1024*1024, wQl + (size_t)1024*1024, KVq*HDq, Dq, 1, 0, 0, 0);
    k_convT2<<<dim3(8, 32, 1), 256, 0, stream>>>(wv + (long long)l*Dq*KVq*HDq, wQh + (size_t)1280*1024, wQl + (size_t)1280*1024, KVq*HDq, Dq, 1, 0, 0, 0);
    k_mgemm3<<<dim3(16, 12, 1), 256, 0, stream>>>(xh, xl, wQh, wQl, qkv, 1536, Dq, Dq, 1536, 0, 0, nullptr, nullptr, Nq);
    k_rope3<<<(Nq * 20 * 32) / 256, 256, 0, stream>>>(qkv, cosT, sinT, qhB, qlB, khB, klB);
    k_convT2<<<dim3(2, 32, Bq*KVq), 256, 0, stream>>>(qkv + 1280, vth, vtl, 1536, Sq,
           KVq, (long long)Sq*1536, HDq, (long long)HDq*Sq);
    k_qk3<<<dim3(8, 8, 32), 256, 0, stream>>>(qhB, qlB, khB, klB, sc);
    k_softmax3<<<(32 * Sq) / 4, 256, 0, stream>>>(sc, ph, pl);
    k_pv3<<<dim3(8, 1, 32), 256, 0, stream>>>(ph, pl, vth, vtl, ath, atl);
    k_convT2<<<dim3(32, 32, 1), 256, 0, stream>>>(wo + (long long)l*Hq*HDq*Dq, wTh, wTl, Dq, Hq*HDq, 1, 0, 0, 0);
    k_mgemm3<<<dim3(16, 8, 1), 256, 0, stream>>>(ath, atl, wTh, wTl, h, Dq, Hq*HDq, Hq*HDq, Dq, 1, 0, nullptr, nullptr, Nq);

    // ---- MoE ----
    k_rmsnorm3<<<Nq, 256, 0, stream>>>(h, ffn_nw + (size_t)l * Dq, xh, xl);
    k_gate<<<Nq / 4, 256, 0, stream>>>(xh, xl, gate + (size_t)l * Dq * Eq, logits);
    k_zero_counts<<<1, 32, 0, stream>>>(counts);
    k_route_count<<<Nq / 256, 256, 0, stream>>>(logits, topw, sel, counts);
    k_scan<<<1, 1, 0, stream>>>(counts, bases, counts2);
    k_route_assign<<<Nq / 256, 256, 0, stream>>>(sel, counts2, bases, row2tok, posof);
    k_gather_us<<<MROW, 256, 0, stream>>>(xh, xl, row2tok, xgh, xgl);
    int last = (l == Lq - 1);   // no routing downstream of last MoE -> 1-pass bf16
    // merged [w1|w3]: expert weight rows 0-2047 = w1, 2048-4095 = w3
    k_convT2<<<dim3(64, 32, 8), 256, 0, stream>>>(w1 + (long long)l*Eq*Dq*Fq, wAh, last ? nullptr : wAl,
           Fq, Dq, 1, (long long)Dq*Fq, 0, (long long)4096*1024);
    k_convT2<<<dim3(64, 32, 8), 256, 0, stream>>>(w3 + (long long)l*Eq*Dq*Fq,
           wAh + (size_t)2048*1024, last ? nullptr : (wAl + (size_t)2048*1024),
           Fq, Dq, 1, (long long)Dq*Fq, 0, (long long)4096*1024);
    if (last) k_mgemm1<<<dim3(16, 32, 8), 256, 0, stream>>>(xgh, wAh, hb, 4096, Dq, Dq, 4096, 0, 1, bases, counts, 0);
    else      k_mgemm3<<<dim3(16, 32, 8), 256, 0, stream>>>(xgh, xgl, wAh, wAl, hb, 4096, Dq, Dq, 4096, 0, 1, bases, counts, 0);
    k_silumul3b<<<4096, 256, 0, stream>>>(hb, h13h, h13l);
    // w2
    k_convT2<<<dim3(32, 64, 8), 256, 0, stream>>>(w2 + (long long)l*Eq*Fq*Dq, wAh, last ? nullptr : wAl,
           Dq, Fq, 1, (long long)Fq*Dq, 0, (long long)Dq*Fq);
    if (last) k_mgemm1<<<dim3(16, 8, 8), 256, 0, stream>>>(h13h, wAh, y, Dq, Fq, Fq, Dq, 0, 1, bases, counts, 0);
    else      k_mgemm3<<<dim3(16, 8, 8), 256, 0, stream>>>(h13h, h13l, wAh, wAl, y, Dq, Fq, Fq, Dq, 0, 1, bases, counts, 0);
    k_moe_combine<<<Nq, 256, 0, stream>>>(h, y, topw, posof);
  }

  // ---- final norm + LM head (1-pass bf16, 2-phase pipelined) ----
  k_rmsnorm3<<<Nq, 256, 0, stream>>>(h, fnw, xh, xl);
  k_convT2<<<dim3(1000, 32, 1), 256, 0, stream>>>(outw, owTh, nullptr, Vq, Dq, 1, 0, 0, 0);
  k_mgemm1<<<dim3(16, 250, 1), 256, 0, stream>>>(xh, owTh, out, Vq, Dq, Dq, Vq, 0, 0, nullptr, nullptr, Nq);
}